// Round 6
// baseline (382.811 us; speedup 1.0000x reference)
//
#include <hip/hip_runtime.h>
#include <math.h>

#define DEV __device__ __forceinline__

typedef unsigned long long u64;
typedef unsigned u32;

// monotone map: float bits -> u32 preserving < order (handles negatives)
DEV u32 fmap(float f) {
    u32 b = __float_as_uint(f);
    return b ^ (u32)(((int)b >> 31) | 0x80000000);
}
// exact inverse of fmap
DEV float funmap(u32 m) {
    u32 b = (m & 0x80000000u) ? (m ^ 0x80000000u) : ~m;
    return __uint_as_float(b);
}

// ---------------- level 1: k=16, 1024 src/graph, C=64, concat 3 -> out [65536,67]
// 256-thread block = 4 waves; each wave processes 4 consecutive targets (ILP).
__global__ __launch_bounds__(256) void knn1_kernel(
    const float* __restrict__ xsrc, const float* __restrict__ pos_s,
    const float* __restrict__ pos_t, const float* __restrict__ x_skip,
    float* __restrict__ out)
{
    const int lane = threadIdx.x & 63;
    const int tb = (blockIdx.x * 4 + (threadIdx.x >> 6)) * 4;  // 4 targets/wave
    const int g = tb >> 12, sbase = g << 10; // 4096 tgts/graph, 1024 srcs/graph

    float qx[4], qy[4], qz[4], qq[4];
    #pragma unroll
    for (int i = 0; i < 4; ++i) {
        qx[i] = pos_t[(tb+i)*3+0];
        qy[i] = pos_t[(tb+i)*3+1];
        qz[i] = pos_t[(tb+i)*3+2];
        qq[i] = qx[i]*qx[i] + qy[i]*qy[i] + qz[i]*qz[i];
    }
    u32 fm[4][16];
    #pragma unroll
    for (int m = 0; m < 16; ++m) {
        const int s = sbase + lane + m*64;
        const float px = pos_s[s*3+0], py = pos_s[s*3+1], pz = pos_s[s*3+2];
        #pragma unroll
        for (int i = 0; i < 4; ++i)
            fm[i][m] = fmap(qq[i] + px*px + py*py + pz*pz
                            - 2.f*(qx[i]*px + qy[i]*py + qz[i]*pz));
    }
    // ---- 4 interleaved exact binary searches for the 16th smallest fmap
    u32 F[4] = {0u, 0u, 0u, 0u};
    for (int b = 31; b >= 0; --b) {
        #pragma unroll
        for (int i = 0; i < 4; ++i) {
            const u32 trial = F[i] | (1u << b);
            int c = 0;
            #pragma unroll
            for (int m = 0; m < 16; ++m)
                c += (int)__popcll(__ballot(fm[i][m] < trial));
            if (c < 16) F[i] = trial;
        }
    }
    // ---- extraction per target: all fmap<F, then lowest-index ties fmap==F
    float y[4], wsum[4];
    #pragma unroll
    for (int i = 0; i < 4; ++i) {
        float ws = 0.f, acc = 0.f;
        int need = 16;
        #pragma unroll
        for (int m = 0; m < 16; ++m) {
            u64 mask = __ballot(fm[i][m] < F[i]);
            while (mask) {
                const int l = __ffsll((long long)mask) - 1; mask &= mask - 1;
                const float d2 = funmap((u32)__builtin_amdgcn_readlane((int)fm[i][m], l));
                const float w = __builtin_amdgcn_rcpf(fmaxf(d2, 1e-16f));
                const int row = sbase + l + m*64;
                ws += w; acc += w * xsrc[(size_t)row * 64 + lane];
                --need;
            }
        }
        #pragma unroll
        for (int m = 0; m < 16; ++m) {
            if (need > 0) {
                u64 mask = __ballot(fm[i][m] == F[i]);
                while (mask && need > 0) {
                    const int l = __ffsll((long long)mask) - 1; mask &= mask - 1;
                    const float d2 = funmap(F[i]);
                    const float w = __builtin_amdgcn_rcpf(fmaxf(d2, 1e-16f));
                    const int row = sbase + l + m*64;
                    ws += w; acc += w * xsrc[(size_t)row * 64 + lane];
                    --need;
                }
            }
        }
        y[i] = acc; wsum[i] = ws;
    }
    #pragma unroll
    for (int i = 0; i < 4; ++i) {
        out[(tb+i)*67 + lane] = y[i] * (1.f / wsum[i]);
        if (lane < 3) out[(tb+i)*67 + 64 + lane] = x_skip[(tb+i)*3 + lane];
    }
}

// ---------------- level 2: k=8, 256 src/graph, C=128, concat 64 -> out [16384,192]
// 256-thread block = 4 waves; each wave processes 2 consecutive targets.
__global__ __launch_bounds__(256) void knn2_kernel(
    const float* __restrict__ xsrc, const float* __restrict__ pos_s,
    const float* __restrict__ pos_t, const float* __restrict__ x_skip,
    float* __restrict__ out)
{
    const int lane = threadIdx.x & 63;
    const int tb = (blockIdx.x * 4 + (threadIdx.x >> 6)) * 2;  // 2 targets/wave
    const int g = tb >> 10, sbase = g << 8;  // 1024 tgts/graph, 256 srcs/graph

    float qx[2], qy[2], qz[2], qq[2];
    #pragma unroll
    for (int i = 0; i < 2; ++i) {
        qx[i] = pos_t[(tb+i)*3+0];
        qy[i] = pos_t[(tb+i)*3+1];
        qz[i] = pos_t[(tb+i)*3+2];
        qq[i] = qx[i]*qx[i] + qy[i]*qy[i] + qz[i]*qz[i];
    }
    u32 fm[2][4];
    #pragma unroll
    for (int m = 0; m < 4; ++m) {
        const int s = sbase + lane + m*64;
        const float px = pos_s[s*3+0], py = pos_s[s*3+1], pz = pos_s[s*3+2];
        #pragma unroll
        for (int i = 0; i < 2; ++i)
            fm[i][m] = fmap(qq[i] + px*px + py*py + pz*pz
                            - 2.f*(qx[i]*px + qy[i]*py + qz[i]*pz));
    }
    u32 F[2] = {0u, 0u};
    for (int b = 31; b >= 0; --b) {
        #pragma unroll
        for (int i = 0; i < 2; ++i) {
            const u32 trial = F[i] | (1u << b);
            int c = 0;
            #pragma unroll
            for (int m = 0; m < 4; ++m)
                c += (int)__popcll(__ballot(fm[i][m] < trial));
            if (c < 8) F[i] = trial;
        }
    }
    #pragma unroll
    for (int i = 0; i < 2; ++i) {
        float ws = 0.f, a0 = 0.f, a1 = 0.f;
        int need = 8;
        #pragma unroll
        for (int m = 0; m < 4; ++m) {
            u64 mask = __ballot(fm[i][m] < F[i]);
            while (mask) {
                const int l = __ffsll((long long)mask) - 1; mask &= mask - 1;
                const float d2 = funmap((u32)__builtin_amdgcn_readlane((int)fm[i][m], l));
                const float w = __builtin_amdgcn_rcpf(fmaxf(d2, 1e-16f));
                const float* xr = xsrc + (size_t)(sbase + l + m*64) * 128;
                ws += w; a0 += w * xr[lane]; a1 += w * xr[lane + 64];
                --need;
            }
        }
        #pragma unroll
        for (int m = 0; m < 4; ++m) {
            if (need > 0) {
                u64 mask = __ballot(fm[i][m] == F[i]);
                while (mask && need > 0) {
                    const int l = __ffsll((long long)mask) - 1; mask &= mask - 1;
                    const float d2 = funmap(F[i]);
                    const float w = __builtin_amdgcn_rcpf(fmaxf(d2, 1e-16f));
                    const float* xr = xsrc + (size_t)(sbase + l + m*64) * 128;
                    ws += w; a0 += w * xr[lane]; a1 += w * xr[lane + 64];
                    --need;
                }
            }
        }
        const float inv = 1.f / ws;
        out[(tb+i)*192 + lane]       = a0 * inv;
        out[(tb+i)*192 + lane + 64]  = a1 * inv;
        out[(tb+i)*192 + 128 + lane] = x_skip[(tb+i)*64 + lane];
    }
}

// ---------------- level 3: k=4, 64 src/graph, C=256 -> out [4096,384]
DEV u64 umin64(u64 a, u64 b) { return a < b ? a : b; }
DEV u64 shfl_xor_u64(u64 k, int off) {
    u32 lo = (u32)k, hi = (u32)(k >> 32);
    lo = (u32)__shfl_xor((int)lo, off, 64);
    hi = (u32)__shfl_xor((int)hi, off, 64);
    return ((u64)hi << 32) | lo;
}
DEV u64 wave_min_u64(u64 v) {
    #pragma unroll
    for (int off = 32; off; off >>= 1)
        v = umin64(v, shfl_xor_u64(v, off));
    return v;
}
DEV u64 make_key(float d2, int idx) { return ((u64)fmap(d2) << 10) | (u32)idx; }
DEV float key_weight(u64 k) {
    return __builtin_amdgcn_rcpf(fmaxf(funmap((u32)(k >> 10)), 1e-16f));
}
DEV int key_row(u64 k) {
    return __builtin_amdgcn_readfirstlane((int)((u32)k & 1023u));
}
#define KMAX 0xFFFFFFFFFFFFFFFFull

__global__ __launch_bounds__(256) void knn3_kernel(
    const float* __restrict__ x, const float* __restrict__ pos_s,
    const float* __restrict__ pos_t, const float* __restrict__ x_skip,
    float* __restrict__ out)
{
    const int lane = threadIdx.x & 63;
    const int t = blockIdx.x * 4 + (threadIdx.x >> 6);
    const int g = t >> 8, sbase = g << 6;   // 256 tgts/graph, 64 srcs/graph
    const float qx = pos_t[t*3+0], qy = pos_t[t*3+1], qz = pos_t[t*3+2];
    const float qq = qx*qx + qy*qy + qz*qz;
    const int s = sbase + lane;
    const float px = pos_s[s*3+0], py = pos_s[s*3+1], pz = pos_s[s*3+2];
    const u64 key = make_key(qq + px*px + py*py + pz*pz
                             - 2.f*(qx*px + qy*py + qz*pz), lane);

    float w[4]; int row[4]; float wsum = 0.f;
    u64 gprev = 0;
    #pragma unroll
    for (int j = 0; j < 4; ++j) {
        gprev = wave_min_u64(key > gprev ? key : KMAX);
        w[j] = key_weight(gprev);
        row[j] = sbase + key_row(gprev);
        wsum += w[j];
    }
    const float inv = 1.f / wsum;
    float y0 = 0.f, y1 = 0.f, y2 = 0.f, y3 = 0.f;
    #pragma unroll
    for (int j = 0; j < 4; ++j) {
        const float* xr = x + (size_t)row[j] * 256;
        y0 += w[j] * xr[lane];
        y1 += w[j] * xr[lane + 64];
        y2 += w[j] * xr[lane + 128];
        y3 += w[j] * xr[lane + 192];
    }
    out[t*384 + lane]       = y0 * inv;
    out[t*384 + lane + 64]  = y1 * inv;
    out[t*384 + lane + 128] = y2 * inv;
    out[t*384 + lane + 192] = y3 * inv;
    out[t*384 + 256 + lane]      = x_skip[t*128 + lane];
    out[t*384 + 256 + 64 + lane] = x_skip[t*128 + 64 + lane];
}

// ---------------- fused 2-layer MLP: out = (tanh(in*Wa^T+ba))*Wb^T+bb
template<int K1, int C1, int C2, int ROWS>
__global__ void mlp2_kernel(
    const float* __restrict__ in, const float* __restrict__ Wa,
    const float* __restrict__ ba, const float* __restrict__ Wb,
    const float* __restrict__ bb, float* __restrict__ out, int N)
{
    __shared__ float xt[ROWS * K1];
    __shared__ float h1[ROWS * C1];
    const int tid = threadIdx.x;
    const int row0 = blockIdx.x * ROWS;

    for (int f = tid; f < ROWS * K1; f += C1)
        xt[f] = in[row0 * K1 + f];
    __syncthreads();

    float acc[ROWS];
    #pragma unroll
    for (int r = 0; r < ROWS; ++r) acc[r] = ba[tid];
    for (int k = 0; k < K1; ++k) {
        const float wv = Wa[tid * K1 + k];
        #pragma unroll
        for (int r = 0; r < ROWS; ++r) acc[r] += xt[r * K1 + k] * wv;
    }
    #pragma unroll
    for (int r = 0; r < ROWS; ++r) h1[r * C1 + tid] = tanhf(acc[r]);
    __syncthreads();

    if (tid < C2) {
        float acc2[ROWS];
        #pragma unroll
        for (int r = 0; r < ROWS; ++r) acc2[r] = bb[tid];
        for (int k = 0; k < C1; ++k) {
            const float wv = Wb[tid * C1 + k];
            #pragma unroll
            for (int r = 0; r < ROWS; ++r) acc2[r] += h1[r * C1 + k] * wv;
        }
        #pragma unroll
        for (int r = 0; r < ROWS; ++r) out[(row0 + r) * C2 + tid] = acc2[r];
    }
}

// ---------------- final 3-layer MLP: 67 -> 64 (tanh) -> 64 (tanh) -> 3
template<int ROWS>
__global__ __launch_bounds__(64) void mlp_final_kernel(
    const float* __restrict__ in,
    const float* __restrict__ Wa, const float* __restrict__ ba,
    const float* __restrict__ Wb, const float* __restrict__ bb,
    const float* __restrict__ Wc, const float* __restrict__ bc,
    float* __restrict__ out, int N)
{
    constexpr int K1 = 67, C = 64;
    __shared__ float xt[ROWS * K1];
    __shared__ float h1[ROWS * C];
    __shared__ float h2[ROWS * 65];
    const int tid = threadIdx.x;
    const int row0 = blockIdx.x * ROWS;

    for (int f = tid; f < ROWS * K1; f += C)
        xt[f] = in[row0 * K1 + f];
    __syncthreads();

    float acc[ROWS];
    #pragma unroll
    for (int r = 0; r < ROWS; ++r) acc[r] = ba[tid];
    for (int k = 0; k < K1; ++k) {
        const float wv = Wa[tid * K1 + k];
        #pragma unroll
        for (int r = 0; r < ROWS; ++r) acc[r] += xt[r * K1 + k] * wv;
    }
    #pragma unroll
    for (int r = 0; r < ROWS; ++r) h1[r * C + tid] = tanhf(acc[r]);
    __syncthreads();

    float acc2[ROWS];
    #pragma unroll
    for (int r = 0; r < ROWS; ++r) acc2[r] = bb[tid];
    for (int k = 0; k < C; ++k) {
        const float wv = Wb[tid * C + k];
        #pragma unroll
        for (int r = 0; r < ROWS; ++r) acc2[r] += h1[r * C + k] * wv;
    }
    #pragma unroll
    for (int r = 0; r < ROWS; ++r) h2[r * 65 + tid] = tanhf(acc2[r]);
    __syncthreads();

    if (tid < ROWS * 3) {
        const int r = tid / 3, o = tid - r * 3;
        float a = bc[o];
        for (int k = 0; k < C; ++k) a += h2[r * 65 + k] * Wc[o * C + k];
        out[(row0 + r) * 3 + o] = a;
    }
}

extern "C" void kernel_launch(void* const* d_in, const int* in_sizes, int n_in,
                              void* d_out, int out_size, void* d_ws, size_t ws_size,
                              hipStream_t stream)
{
    const float* x       = (const float*)d_in[0];
    const float* pos     = (const float*)d_in[1];
    const float* x_skip2 = (const float*)d_in[3];
    const float* pos2    = (const float*)d_in[4];
    const float* x_skip1 = (const float*)d_in[6];
    const float* pos1    = (const float*)d_in[7];
    const float* x_skip0 = (const float*)d_in[9];
    const float* pos0    = (const float*)d_in[10];
    const float* W3a = (const float*)d_in[12]; const float* b3a = (const float*)d_in[13];
    const float* W3b = (const float*)d_in[14]; const float* b3b = (const float*)d_in[15];
    const float* W2a = (const float*)d_in[16]; const float* b2a = (const float*)d_in[17];
    const float* W2b = (const float*)d_in[18]; const float* b2b = (const float*)d_in[19];
    const float* W1a = (const float*)d_in[20]; const float* b1a = (const float*)d_in[21];
    const float* W1b = (const float*)d_in[22]; const float* b1b = (const float*)d_in[23];
    const float* W1c = (const float*)d_in[24]; const float* b1c = (const float*)d_in[25];

    float* buf1 = (float*)d_ws;
    float* buf2 = buf1 + (size_t)65536 * 67;

    // level 3
    knn3_kernel<<<1024, 256, 0, stream>>>(x, pos, pos2, x_skip2, buf1);
    mlp2_kernel<384,128,128,16><<<4096/16, 128, 0, stream>>>(buf1, W3a, b3a, W3b, b3b, buf2, 4096);
    // level 2
    knn2_kernel<<<2048, 256, 0, stream>>>(buf2, pos2, pos1, x_skip1, buf1);
    mlp2_kernel<192,64,64,16><<<16384/16, 64, 0, stream>>>(buf1, W2a, b2a, W2b, b2b, buf2, 16384);
    // level 1
    knn1_kernel<<<4096, 256, 0, stream>>>(buf2, pos1, pos0, x_skip0, buf1);
    mlp_final_kernel<16><<<65536/16, 64, 0, stream>>>(buf1, W1a, b1a, W1b, b1b, W1c, b1c,
                                                      (float*)d_out, 65536);
}

// Round 8
// 319.095 us; speedup vs baseline: 1.1997x; 1.1997x over previous
//
#include <hip/hip_runtime.h>
#include <math.h>

#define DEV __device__ __forceinline__

typedef unsigned long long u64;
typedef unsigned u32;

// monotone map: float bits -> u32 preserving < order (handles negatives)
DEV u32 fmap(float f) {
    u32 b = __float_as_uint(f);
    return b ^ (u32)(((int)b >> 31) | 0x80000000);
}
// exact inverse of fmap
DEV float funmap(u32 m) {
    u32 b = (m & 0x80000000u) ? (m ^ 0x80000000u) : ~m;
    return __uint_as_float(b);
}
DEV u32 umin_(u32 a, u32 b) { return a < b ? a : b; }
DEV u32 umax_(u32 a, u32 b) { return a > b ? a : b; }

// ---- BIT-EXACT distance: explicit _rn intrinsics; identical results in every
// kernel regardless of context (no contraction/reassociation possible).
DEV float qnorm2(float qx, float qy, float qz) {
    return __fmaf_rn(qx, qx, __fmaf_rn(qy, qy, __fmul_rn(qz, qz)));
}
DEV float dist2(float qx, float qy, float qz, float qq,
                float px, float py, float pz) {
    const float pp = __fmaf_rn(px, px, __fmaf_rn(py, py, __fmul_rn(pz, pz)));
    const float qp = __fmaf_rn(qx, px, __fmaf_rn(qy, py, __fmul_rn(qz, pz)));
    return __fadd_rn(__fadd_rn(qq, pp), __fmul_rn(-2.f, qp));
}

// ============ selection kernel: one thread = one target ====================
// Maintains exact top-K fmap values (branchless sorted insert), writes the
// K-th smallest key F[t]. No cross-lane ops at all.
template<int K, int NSRC, int LOG_TPG>
__global__ __launch_bounds__(256) void knn_select(
    const float* __restrict__ pos_s, const float* __restrict__ pos_t,
    u32* __restrict__ Fout)
{
    __shared__ float4 sp[NSRC];
    const int t = blockIdx.x * 256 + threadIdx.x;
    const int g = t >> LOG_TPG, sbase = g * NSRC;
    for (int i = threadIdx.x; i < NSRC; i += 256) {
        const float* p = pos_s + (size_t)(sbase + i) * 3;
        sp[i] = make_float4(p[0], p[1], p[2], 0.f);
    }
    __syncthreads();
    const float qx = pos_t[t*3+0], qy = pos_t[t*3+1], qz = pos_t[t*3+2];
    const float qq = qnorm2(qx, qy, qz);

    u32 r[K];
    #pragma unroll
    for (int j = 0; j < K; ++j) r[j] = 0xFFFFFFFFu;

    #pragma unroll 4
    for (int s = 0; s < NSRC; ++s) {
        const float4 p = sp[s];
        u32 c = fmap(dist2(qx, qy, qz, qq, p.x, p.y, p.z));
        // branchless sorted insert (ascending); carries out the max
        #pragma unroll
        for (int j = 0; j < K; ++j) {
            const u32 lo = umin_(r[j], c);
            c = umax_(r[j], c);
            r[j] = lo;
        }
    }
    Fout[t] = r[K-1];
}

// ============ gather kernels: one wave = one target (R4 path, F given) =====

// level 1: k=16, 1024 src/graph, C=64, concat 3 -> out [65536,67]
__global__ __launch_bounds__(256) void knn1_gather(
    const float* __restrict__ xsrc, const float* __restrict__ pos_s,
    const float* __restrict__ pos_t, const float* __restrict__ x_skip,
    const u32* __restrict__ Fbuf, float* __restrict__ out)
{
    const int lane = threadIdx.x & 63;
    const int t = blockIdx.x * 4 + (threadIdx.x >> 6);
    const int g = t >> 12, sbase = g << 10;
    const float qx = pos_t[t*3+0], qy = pos_t[t*3+1], qz = pos_t[t*3+2];
    const float qq = qnorm2(qx, qy, qz);
    u32 fm[16];
    #pragma unroll
    for (int m = 0; m < 16; ++m) {
        const int s = sbase + lane + m*64;
        fm[m] = fmap(dist2(qx, qy, qz, qq,
                           pos_s[s*3+0], pos_s[s*3+1], pos_s[s*3+2]));
    }
    const u32 F = Fbuf[t];

    float wsum = 0.f, y = 0.f;
    int need = 16;
    #pragma unroll
    for (int m = 0; m < 16; ++m) {
        u64 mask = __ballot(fm[m] < F);
        while (mask && need > 0) {
            const int l = __ffsll((long long)mask) - 1; mask &= mask - 1;
            const float d2 = funmap((u32)__builtin_amdgcn_readlane((int)fm[m], l));
            const float w = __builtin_amdgcn_rcpf(fmaxf(d2, 1e-16f));
            const int row = sbase + l + m*64;
            wsum += w; y += w * xsrc[(size_t)row * 64 + lane];
            --need;
        }
    }
    #pragma unroll
    for (int m = 0; m < 16; ++m) {
        if (need > 0) {
            u64 mask = __ballot(fm[m] == F);
            while (mask && need > 0) {
                const int l = __ffsll((long long)mask) - 1; mask &= mask - 1;
                const float d2 = funmap(F);
                const float w = __builtin_amdgcn_rcpf(fmaxf(d2, 1e-16f));
                const int row = sbase + l + m*64;
                wsum += w; y += w * xsrc[(size_t)row * 64 + lane];
                --need;
            }
        }
    }
    out[t*67 + lane] = y * (1.f / wsum);
    if (lane < 3) out[t*67 + 64 + lane] = x_skip[t*3 + lane];
}

// level 2: k=8, 256 src/graph, C=128, concat 64 -> out [16384,192]
__global__ __launch_bounds__(256) void knn2_gather(
    const float* __restrict__ xsrc, const float* __restrict__ pos_s,
    const float* __restrict__ pos_t, const float* __restrict__ x_skip,
    const u32* __restrict__ Fbuf, float* __restrict__ out)
{
    const int lane = threadIdx.x & 63;
    const int t = blockIdx.x * 4 + (threadIdx.x >> 6);
    const int g = t >> 10, sbase = g << 8;
    const float qx = pos_t[t*3+0], qy = pos_t[t*3+1], qz = pos_t[t*3+2];
    const float qq = qnorm2(qx, qy, qz);
    u32 fm[4];
    #pragma unroll
    for (int m = 0; m < 4; ++m) {
        const int s = sbase + lane + m*64;
        fm[m] = fmap(dist2(qx, qy, qz, qq,
                           pos_s[s*3+0], pos_s[s*3+1], pos_s[s*3+2]));
    }
    const u32 F = Fbuf[t];

    float wsum = 0.f, y0 = 0.f, y1 = 0.f;
    int need = 8;
    #pragma unroll
    for (int m = 0; m < 4; ++m) {
        u64 mask = __ballot(fm[m] < F);
        while (mask && need > 0) {
            const int l = __ffsll((long long)mask) - 1; mask &= mask - 1;
            const float d2 = funmap((u32)__builtin_amdgcn_readlane((int)fm[m], l));
            const float w = __builtin_amdgcn_rcpf(fmaxf(d2, 1e-16f));
            const float* xr = xsrc + (size_t)(sbase + l + m*64) * 128;
            wsum += w; y0 += w * xr[lane]; y1 += w * xr[lane + 64];
            --need;
        }
    }
    #pragma unroll
    for (int m = 0; m < 4; ++m) {
        if (need > 0) {
            u64 mask = __ballot(fm[m] == F);
            while (mask && need > 0) {
                const int l = __ffsll((long long)mask) - 1; mask &= mask - 1;
                const float d2 = funmap(F);
                const float w = __builtin_amdgcn_rcpf(fmaxf(d2, 1e-16f));
                const float* xr = xsrc + (size_t)(sbase + l + m*64) * 128;
                wsum += w; y0 += w * xr[lane]; y1 += w * xr[lane + 64];
                --need;
            }
        }
    }
    const float inv = 1.f / wsum;
    out[t*192 + lane]      = y0 * inv;
    out[t*192 + lane + 64] = y1 * inv;
    out[t*192 + 128 + lane] = x_skip[t*64 + lane];
}

// ---------------- level 3: k=4, 64 src/graph, C=256 -> out [4096,384]
DEV u64 umin64(u64 a, u64 b) { return a < b ? a : b; }
DEV u64 shfl_xor_u64(u64 k, int off) {
    u32 lo = (u32)k, hi = (u32)(k >> 32);
    lo = (u32)__shfl_xor((int)lo, off, 64);
    hi = (u32)__shfl_xor((int)hi, off, 64);
    return ((u64)hi << 32) | lo;
}
DEV u64 wave_min_u64(u64 v) {
    #pragma unroll
    for (int off = 32; off; off >>= 1)
        v = umin64(v, shfl_xor_u64(v, off));
    return v;
}
DEV u64 make_key(float d2, int idx) { return ((u64)fmap(d2) << 10) | (u32)idx; }
DEV float key_weight(u64 k) {
    return __builtin_amdgcn_rcpf(fmaxf(funmap((u32)(k >> 10)), 1e-16f));
}
DEV int key_row(u64 k) {
    return __builtin_amdgcn_readfirstlane((int)((u32)k & 1023u));
}
#define KMAX 0xFFFFFFFFFFFFFFFFull

__global__ __launch_bounds__(256) void knn3_kernel(
    const float* __restrict__ x, const float* __restrict__ pos_s,
    const float* __restrict__ pos_t, const float* __restrict__ x_skip,
    float* __restrict__ out)
{
    const int lane = threadIdx.x & 63;
    const int t = blockIdx.x * 4 + (threadIdx.x >> 6);
    const int g = t >> 8, sbase = g << 6;
    const float qx = pos_t[t*3+0], qy = pos_t[t*3+1], qz = pos_t[t*3+2];
    const float qq = qnorm2(qx, qy, qz);
    const int s = sbase + lane;
    const u64 key = make_key(dist2(qx, qy, qz, qq,
                                   pos_s[s*3+0], pos_s[s*3+1], pos_s[s*3+2]), lane);

    float w[4]; int row[4]; float wsum = 0.f;
    u64 gprev = 0;
    #pragma unroll
    for (int j = 0; j < 4; ++j) {
        gprev = wave_min_u64(key > gprev ? key : KMAX);
        w[j] = key_weight(gprev);
        row[j] = sbase + key_row(gprev);
        wsum += w[j];
    }
    const float inv = 1.f / wsum;
    float y0 = 0.f, y1 = 0.f, y2 = 0.f, y3 = 0.f;
    #pragma unroll
    for (int j = 0; j < 4; ++j) {
        const float* xr = x + (size_t)row[j] * 256;
        y0 += w[j] * xr[lane];
        y1 += w[j] * xr[lane + 64];
        y2 += w[j] * xr[lane + 128];
        y3 += w[j] * xr[lane + 192];
    }
    out[t*384 + lane]       = y0 * inv;
    out[t*384 + lane + 64]  = y1 * inv;
    out[t*384 + lane + 128] = y2 * inv;
    out[t*384 + lane + 192] = y3 * inv;
    out[t*384 + 256 + lane]      = x_skip[t*128 + lane];
    out[t*384 + 256 + 64 + lane] = x_skip[t*128 + 64 + lane];
}

// ---------------- fused 2-layer MLP: out = (tanh(in*Wa^T+ba))*Wb^T+bb
template<int K1, int C1, int C2, int ROWS>
__global__ void mlp2_kernel(
    const float* __restrict__ in, const float* __restrict__ Wa,
    const float* __restrict__ ba, const float* __restrict__ Wb,
    const float* __restrict__ bb, float* __restrict__ out, int N)
{
    __shared__ float xt[ROWS * K1];
    __shared__ float h1[ROWS * C1];
    const int tid = threadIdx.x;
    const int row0 = blockIdx.x * ROWS;

    for (int f = tid; f < ROWS * K1; f += C1)
        xt[f] = in[row0 * K1 + f];
    __syncthreads();

    float acc[ROWS];
    #pragma unroll
    for (int r = 0; r < ROWS; ++r) acc[r] = ba[tid];
    for (int k = 0; k < K1; ++k) {
        const float wv = Wa[tid * K1 + k];
        #pragma unroll
        for (int r = 0; r < ROWS; ++r) acc[r] += xt[r * K1 + k] * wv;
    }
    #pragma unroll
    for (int r = 0; r < ROWS; ++r) h1[r * C1 + tid] = tanhf(acc[r]);
    __syncthreads();

    if (tid < C2) {
        float acc2[ROWS];
        #pragma unroll
        for (int r = 0; r < ROWS; ++r) acc2[r] = bb[tid];
        for (int k = 0; k < C1; ++k) {
            const float wv = Wb[tid * C1 + k];
            #pragma unroll
            for (int r = 0; r < ROWS; ++r) acc2[r] += h1[r * C1 + k] * wv;
        }
        #pragma unroll
        for (int r = 0; r < ROWS; ++r) out[(row0 + r) * C2 + tid] = acc2[r];
    }
}

// ---------------- final 3-layer MLP: 67 -> 64 (tanh) -> 64 (tanh) -> 3
template<int ROWS>
__global__ __launch_bounds__(64) void mlp_final_kernel(
    const float* __restrict__ in,
    const float* __restrict__ Wa, const float* __restrict__ ba,
    const float* __restrict__ Wb, const float* __restrict__ bb,
    const float* __restrict__ Wc, const float* __restrict__ bc,
    float* __restrict__ out, int N)
{
    constexpr int K1 = 67, C = 64;
    __shared__ float xt[ROWS * K1];
    __shared__ float h1[ROWS * C];
    __shared__ float h2[ROWS * 65];
    const int tid = threadIdx.x;
    const int row0 = blockIdx.x * ROWS;

    for (int f = tid; f < ROWS * K1; f += C)
        xt[f] = in[row0 * K1 + f];
    __syncthreads();

    float acc[ROWS];
    #pragma unroll
    for (int r = 0; r < ROWS; ++r) acc[r] = ba[tid];
    for (int k = 0; k < K1; ++k) {
        const float wv = Wa[tid * K1 + k];
        #pragma unroll
        for (int r = 0; r < ROWS; ++r) acc[r] += xt[r * K1 + k] * wv;
    }
    #pragma unroll
    for (int r = 0; r < ROWS; ++r) h1[r * C + tid] = tanhf(acc[r]);
    __syncthreads();

    float acc2[ROWS];
    #pragma unroll
    for (int r = 0; r < ROWS; ++r) acc2[r] = bb[tid];
    for (int k = 0; k < C; ++k) {
        const float wv = Wb[tid * C + k];
        #pragma unroll
        for (int r = 0; r < ROWS; ++r) acc2[r] += h1[r * C + k] * wv;
    }
    #pragma unroll
    for (int r = 0; r < ROWS; ++r) h2[r * 65 + tid] = tanhf(acc2[r]);
    __syncthreads();

    if (tid < ROWS * 3) {
        const int r = tid / 3, o = tid - r * 3;
        float a = bc[o];
        for (int k = 0; k < C; ++k) a += h2[r * 65 + k] * Wc[o * C + k];
        out[(row0 + r) * 3 + o] = a;
    }
}

extern "C" void kernel_launch(void* const* d_in, const int* in_sizes, int n_in,
                              void* d_out, int out_size, void* d_ws, size_t ws_size,
                              hipStream_t stream)
{
    const float* x       = (const float*)d_in[0];
    const float* pos     = (const float*)d_in[1];
    const float* x_skip2 = (const float*)d_in[3];
    const float* pos2    = (const float*)d_in[4];
    const float* x_skip1 = (const float*)d_in[6];
    const float* pos1    = (const float*)d_in[7];
    const float* x_skip0 = (const float*)d_in[9];
    const float* pos0    = (const float*)d_in[10];
    const float* W3a = (const float*)d_in[12]; const float* b3a = (const float*)d_in[13];
    const float* W3b = (const float*)d_in[14]; const float* b3b = (const float*)d_in[15];
    const float* W2a = (const float*)d_in[16]; const float* b2a = (const float*)d_in[17];
    const float* W2b = (const float*)d_in[18]; const float* b2b = (const float*)d_in[19];
    const float* W1a = (const float*)d_in[20]; const float* b1a = (const float*)d_in[21];
    const float* W1b = (const float*)d_in[22]; const float* b1b = (const float*)d_in[23];
    const float* W1c = (const float*)d_in[24]; const float* b1c = (const float*)d_in[25];

    float* buf1 = (float*)d_ws;                        // 65536*67 floats
    float* buf2 = buf1 + (size_t)65536 * 67;           // 16384*64 floats
    u32*   F1   = (u32*)(buf2 + (size_t)16384 * 64);   // 65536 u32
    u32*   F2   = F1 + 65536;                          // 16384 u32

    // level 3
    knn3_kernel<<<1024, 256, 0, stream>>>(x, pos, pos2, x_skip2, buf1);
    mlp2_kernel<384,128,128,16><<<4096/16, 128, 0, stream>>>(buf1, W3a, b3a, W3b, b3b, buf2, 4096);
    // level 2: select (lane-per-target) + gather (wave-per-target)
    knn_select<8, 256, 10><<<16384/256, 256, 0, stream>>>(pos2, pos1, F2);
    knn2_gather<<<4096, 256, 0, stream>>>(buf2, pos2, pos1, x_skip1, F2, buf1);
    mlp2_kernel<192,64,64,16><<<16384/16, 64, 0, stream>>>(buf1, W2a, b2a, W2b, b2b, buf2, 16384);
    // level 1
    knn_select<16, 1024, 12><<<65536/256, 256, 0, stream>>>(pos1, pos0, F1);
    knn1_gather<<<16384, 256, 0, stream>>>(buf2, pos1, pos0, x_skip0, F1, buf1);
    mlp_final_kernel<16><<<65536/16, 64, 0, stream>>>(buf1, W1a, b1a, W1b, b1b, W1c, b1c,
                                                      (float*)d_out, 65536);
}

// Round 9
// 290.218 us; speedup vs baseline: 1.3190x; 1.0995x over previous
//
#include <hip/hip_runtime.h>
#include <math.h>

#define DEV __device__ __forceinline__

typedef unsigned long long u64;
typedef unsigned u32;

// monotone map: float bits -> u32 preserving < order (handles negatives)
DEV u32 fmap(float f) {
    u32 b = __float_as_uint(f);
    return b ^ (u32)(((int)b >> 31) | 0x80000000);
}
// exact inverse of fmap
DEV float funmap(u32 m) {
    u32 b = (m & 0x80000000u) ? (m ^ 0x80000000u) : ~m;
    return __uint_as_float(b);
}
DEV u32 umin_(u32 a, u32 b) { return __builtin_elementwise_min(a, b); }
DEV u32 umax_(u32 a, u32 b) { return __builtin_elementwise_max(a, b); }

// ---- BIT-EXACT distance pieces: explicit _rn intrinsics, composed the same
// way in every kernel. pnorm2/qdot/dist2_core are the single source of truth.
DEV float pnorm2(float x, float y, float z) {
    return __fmaf_rn(x, x, __fmaf_rn(y, y, __fmul_rn(z, z)));
}
DEV float qdot(float qx, float qy, float qz, float px, float py, float pz) {
    return __fmaf_rn(qx, px, __fmaf_rn(qy, py, __fmul_rn(qz, pz)));
}
DEV float dist2_core(float qq, float pp, float qp) {
    return __fadd_rn(__fadd_rn(qq, pp), __fmul_rn(-2.f, qp));
}
DEV float dist2(float qx, float qy, float qz, float qq,
                float px, float py, float pz) {
    return dist2_core(qq, pnorm2(px, py, pz), qdot(qx, qy, qz, px, py, pz));
}

// ============ selection kernel: TPT threads per target =====================
// Each of the TPT threads scans NSRC/TPT sources keeping its exact top-K
// (branchless sorted insert, v_min/v_max). Lists merge in LDS; thread sub==0
// walks K steps of a 4-way merge to produce the exact k-th smallest key F[t].
template<int K, int NSRC, int LOG_TPG>
__global__ __launch_bounds__(256) void knn_select(
    const float* __restrict__ pos_s, const float* __restrict__ pos_t,
    u32* __restrict__ Fout)
{
    constexpr int TPT = 4;
    constexpr int TPB = 256 / TPT;          // targets per block
    constexpr int SL  = NSRC / TPT;         // slice length per thread
    constexpr int STRIDE = TPT * K + 1;     // +1 pad: conflict-free merge reads
    __shared__ float4 sp[NSRC];
    __shared__ u32 lists[TPB * STRIDE];

    const int tid = threadIdx.x;
    const int w = tid >> 2, sub = tid & 3;
    const int t = blockIdx.x * TPB + w;
    const int g = t >> LOG_TPG, sbase = g * NSRC;

    for (int i = tid; i < NSRC; i += 256) {
        const float* p = pos_s + (size_t)(sbase + i) * 3;
        const float px = p[0], py = p[1], pz = p[2];
        sp[i] = make_float4(px, py, pz, pnorm2(px, py, pz));
    }
    __syncthreads();

    const float qx = pos_t[t*3+0], qy = pos_t[t*3+1], qz = pos_t[t*3+2];
    const float qq = pnorm2(qx, qy, qz);

    u32 r[K];
    #pragma unroll
    for (int j = 0; j < K; ++j) r[j] = 0xFFFFFFFFu;

    #pragma unroll 4
    for (int s = 0; s < SL; ++s) {
        const float4 p = sp[sub * SL + s];
        u32 c = fmap(dist2_core(qq, p.w, qdot(qx, qy, qz, p.x, p.y, p.z)));
        #pragma unroll
        for (int j = 0; j < K; ++j) {
            const u32 lo = umin_(r[j], c);
            c = umax_(r[j], c);
            r[j] = lo;
        }
    }
    u32* Lw = lists + w * STRIDE;
    #pragma unroll
    for (int j = 0; j < K; ++j) Lw[sub * K + j] = r[j];
    __syncthreads();

    if (sub == 0) {
        int i0 = 1, i1 = 1, i2 = 1, i3 = 1;
        u32 h0 = Lw[0*K], h1 = Lw[1*K], h2 = Lw[2*K], h3 = Lw[3*K];
        u32 F = 0;
        #pragma unroll
        for (int step = 0; step < K; ++step) {
            const u32 m = umin_(umin_(h0, h1), umin_(h2, h3));
            F = m;
            if (step < K - 1) {
                if (h0 == m)      { h0 = (i0 < K) ? Lw[0*K + i0] : 0xFFFFFFFFu; ++i0; }
                else if (h1 == m) { h1 = (i1 < K) ? Lw[1*K + i1] : 0xFFFFFFFFu; ++i1; }
                else if (h2 == m) { h2 = (i2 < K) ? Lw[2*K + i2] : 0xFFFFFFFFu; ++i2; }
                else              { h3 = (i3 < K) ? Lw[3*K + i3] : 0xFFFFFFFFu; ++i3; }
            }
        }
        Fout[t] = F;
    }
}

// ============ gather kernels: one wave = one target (F given) ==============

// level 1: k=16, 1024 src/graph, C=64, concat 3 -> out [65536,67]
__global__ __launch_bounds__(256) void knn1_gather(
    const float* __restrict__ xsrc, const float* __restrict__ pos_s,
    const float* __restrict__ pos_t, const float* __restrict__ x_skip,
    const u32* __restrict__ Fbuf, float* __restrict__ out)
{
    const int lane = threadIdx.x & 63;
    const int t = blockIdx.x * 4 + (threadIdx.x >> 6);
    const int g = t >> 12, sbase = g << 10;
    const float qx = pos_t[t*3+0], qy = pos_t[t*3+1], qz = pos_t[t*3+2];
    const float qq = pnorm2(qx, qy, qz);
    u32 fm[16];
    #pragma unroll
    for (int m = 0; m < 16; ++m) {
        const int s = sbase + lane + m*64;
        fm[m] = fmap(dist2(qx, qy, qz, qq,
                           pos_s[s*3+0], pos_s[s*3+1], pos_s[s*3+2]));
    }
    const u32 F = Fbuf[t];

    float wsum = 0.f, y = 0.f;
    int need = 16;
    #pragma unroll
    for (int m = 0; m < 16; ++m) {
        u64 mask = __ballot(fm[m] < F);
        while (mask && need > 0) {
            const int l = __ffsll((long long)mask) - 1; mask &= mask - 1;
            const float d2 = funmap((u32)__builtin_amdgcn_readlane((int)fm[m], l));
            const float w = __builtin_amdgcn_rcpf(fmaxf(d2, 1e-16f));
            const int row = sbase + l + m*64;
            wsum += w; y += w * xsrc[(size_t)row * 64 + lane];
            --need;
        }
    }
    #pragma unroll
    for (int m = 0; m < 16; ++m) {
        if (need > 0) {
            u64 mask = __ballot(fm[m] == F);
            while (mask && need > 0) {
                const int l = __ffsll((long long)mask) - 1; mask &= mask - 1;
                const float d2 = funmap(F);
                const float w = __builtin_amdgcn_rcpf(fmaxf(d2, 1e-16f));
                const int row = sbase + l + m*64;
                wsum += w; y += w * xsrc[(size_t)row * 64 + lane];
                --need;
            }
        }
    }
    out[t*67 + lane] = y * (1.f / wsum);
    if (lane < 3) out[t*67 + 64 + lane] = x_skip[t*3 + lane];
}

// level 2: k=8, 256 src/graph, C=128, concat 64 -> out [16384,192]
__global__ __launch_bounds__(256) void knn2_gather(
    const float* __restrict__ xsrc, const float* __restrict__ pos_s,
    const float* __restrict__ pos_t, const float* __restrict__ x_skip,
    const u32* __restrict__ Fbuf, float* __restrict__ out)
{
    const int lane = threadIdx.x & 63;
    const int t = blockIdx.x * 4 + (threadIdx.x >> 6);
    const int g = t >> 10, sbase = g << 8;
    const float qx = pos_t[t*3+0], qy = pos_t[t*3+1], qz = pos_t[t*3+2];
    const float qq = pnorm2(qx, qy, qz);
    u32 fm[4];
    #pragma unroll
    for (int m = 0; m < 4; ++m) {
        const int s = sbase + lane + m*64;
        fm[m] = fmap(dist2(qx, qy, qz, qq,
                           pos_s[s*3+0], pos_s[s*3+1], pos_s[s*3+2]));
    }
    const u32 F = Fbuf[t];

    float wsum = 0.f, y0 = 0.f, y1 = 0.f;
    int need = 8;
    #pragma unroll
    for (int m = 0; m < 4; ++m) {
        u64 mask = __ballot(fm[m] < F);
        while (mask && need > 0) {
            const int l = __ffsll((long long)mask) - 1; mask &= mask - 1;
            const float d2 = funmap((u32)__builtin_amdgcn_readlane((int)fm[m], l));
            const float w = __builtin_amdgcn_rcpf(fmaxf(d2, 1e-16f));
            const float* xr = xsrc + (size_t)(sbase + l + m*64) * 128;
            wsum += w; y0 += w * xr[lane]; y1 += w * xr[lane + 64];
            --need;
        }
    }
    #pragma unroll
    for (int m = 0; m < 4; ++m) {
        if (need > 0) {
            u64 mask = __ballot(fm[m] == F);
            while (mask && need > 0) {
                const int l = __ffsll((long long)mask) - 1; mask &= mask - 1;
                const float d2 = funmap(F);
                const float w = __builtin_amdgcn_rcpf(fmaxf(d2, 1e-16f));
                const float* xr = xsrc + (size_t)(sbase + l + m*64) * 128;
                wsum += w; y0 += w * xr[lane]; y1 += w * xr[lane + 64];
                --need;
            }
        }
    }
    const float inv = 1.f / wsum;
    out[t*192 + lane]      = y0 * inv;
    out[t*192 + lane + 64] = y1 * inv;
    out[t*192 + 128 + lane] = x_skip[t*64 + lane];
}

// ---------------- level 3: k=4, 64 src/graph, C=256 -> out [4096,384]
DEV u64 umin64(u64 a, u64 b) { return a < b ? a : b; }
DEV u64 shfl_xor_u64(u64 k, int off) {
    u32 lo = (u32)k, hi = (u32)(k >> 32);
    lo = (u32)__shfl_xor((int)lo, off, 64);
    hi = (u32)__shfl_xor((int)hi, off, 64);
    return ((u64)hi << 32) | lo;
}
DEV u64 wave_min_u64(u64 v) {
    #pragma unroll
    for (int off = 32; off; off >>= 1)
        v = umin64(v, shfl_xor_u64(v, off));
    return v;
}
DEV u64 make_key(float d2, int idx) { return ((u64)fmap(d2) << 10) | (u32)idx; }
DEV float key_weight(u64 k) {
    return __builtin_amdgcn_rcpf(fmaxf(funmap((u32)(k >> 10)), 1e-16f));
}
DEV int key_row(u64 k) {
    return __builtin_amdgcn_readfirstlane((int)((u32)k & 1023u));
}
#define KMAX 0xFFFFFFFFFFFFFFFFull

__global__ __launch_bounds__(256) void knn3_kernel(
    const float* __restrict__ x, const float* __restrict__ pos_s,
    const float* __restrict__ pos_t, const float* __restrict__ x_skip,
    float* __restrict__ out)
{
    const int lane = threadIdx.x & 63;
    const int t = blockIdx.x * 4 + (threadIdx.x >> 6);
    const int g = t >> 8, sbase = g << 6;
    const float qx = pos_t[t*3+0], qy = pos_t[t*3+1], qz = pos_t[t*3+2];
    const float qq = pnorm2(qx, qy, qz);
    const int s = sbase + lane;
    const u64 key = make_key(dist2(qx, qy, qz, qq,
                                   pos_s[s*3+0], pos_s[s*3+1], pos_s[s*3+2]), lane);

    float w[4]; int row[4]; float wsum = 0.f;
    u64 gprev = 0;
    #pragma unroll
    for (int j = 0; j < 4; ++j) {
        gprev = wave_min_u64(key > gprev ? key : KMAX);
        w[j] = key_weight(gprev);
        row[j] = sbase + key_row(gprev);
        wsum += w[j];
    }
    const float inv = 1.f / wsum;
    float y0 = 0.f, y1 = 0.f, y2 = 0.f, y3 = 0.f;
    #pragma unroll
    for (int j = 0; j < 4; ++j) {
        const float* xr = x + (size_t)row[j] * 256;
        y0 += w[j] * xr[lane];
        y1 += w[j] * xr[lane + 64];
        y2 += w[j] * xr[lane + 128];
        y3 += w[j] * xr[lane + 192];
    }
    out[t*384 + lane]       = y0 * inv;
    out[t*384 + lane + 64]  = y1 * inv;
    out[t*384 + lane + 128] = y2 * inv;
    out[t*384 + lane + 192] = y3 * inv;
    out[t*384 + 256 + lane]      = x_skip[t*128 + lane];
    out[t*384 + 256 + 64 + lane] = x_skip[t*128 + 64 + lane];
}

// ---------------- fused 2-layer MLP: out = (tanh(in*Wa^T+ba))*Wb^T+bb
template<int K1, int C1, int C2, int ROWS>
__global__ void mlp2_kernel(
    const float* __restrict__ in, const float* __restrict__ Wa,
    const float* __restrict__ ba, const float* __restrict__ Wb,
    const float* __restrict__ bb, float* __restrict__ out, int N)
{
    __shared__ float xt[ROWS * K1];
    __shared__ float h1[ROWS * C1];
    const int tid = threadIdx.x;
    const int row0 = blockIdx.x * ROWS;

    for (int f = tid; f < ROWS * K1; f += C1)
        xt[f] = in[row0 * K1 + f];
    __syncthreads();

    float acc[ROWS];
    #pragma unroll
    for (int r = 0; r < ROWS; ++r) acc[r] = ba[tid];
    for (int k = 0; k < K1; ++k) {
        const float wv = Wa[tid * K1 + k];
        #pragma unroll
        for (int r = 0; r < ROWS; ++r) acc[r] += xt[r * K1 + k] * wv;
    }
    #pragma unroll
    for (int r = 0; r < ROWS; ++r) h1[r * C1 + tid] = tanhf(acc[r]);
    __syncthreads();

    if (tid < C2) {
        float acc2[ROWS];
        #pragma unroll
        for (int r = 0; r < ROWS; ++r) acc2[r] = bb[tid];
        for (int k = 0; k < C1; ++k) {
            const float wv = Wb[tid * C1 + k];
            #pragma unroll
            for (int r = 0; r < ROWS; ++r) acc2[r] += h1[r * C1 + k] * wv;
        }
        #pragma unroll
        for (int r = 0; r < ROWS; ++r) out[(row0 + r) * C2 + tid] = acc2[r];
    }
}

// ---------------- final 3-layer MLP: 67 -> 64 (tanh) -> 64 (tanh) -> 3
template<int ROWS>
__global__ __launch_bounds__(64) void mlp_final_kernel(
    const float* __restrict__ in,
    const float* __restrict__ Wa, const float* __restrict__ ba,
    const float* __restrict__ Wb, const float* __restrict__ bb,
    const float* __restrict__ Wc, const float* __restrict__ bc,
    float* __restrict__ out, int N)
{
    constexpr int K1 = 67, C = 64;
    __shared__ float xt[ROWS * K1];
    __shared__ float h1[ROWS * C];
    __shared__ float h2[ROWS * 65];
    const int tid = threadIdx.x;
    const int row0 = blockIdx.x * ROWS;

    for (int f = tid; f < ROWS * K1; f += C)
        xt[f] = in[row0 * K1 + f];
    __syncthreads();

    float acc[ROWS];
    #pragma unroll
    for (int r = 0; r < ROWS; ++r) acc[r] = ba[tid];
    for (int k = 0; k < K1; ++k) {
        const float wv = Wa[tid * K1 + k];
        #pragma unroll
        for (int r = 0; r < ROWS; ++r) acc[r] += xt[r * K1 + k] * wv;
    }
    #pragma unroll
    for (int r = 0; r < ROWS; ++r) h1[r * C + tid] = tanhf(acc[r]);
    __syncthreads();

    float acc2[ROWS];
    #pragma unroll
    for (int r = 0; r < ROWS; ++r) acc2[r] = bb[tid];
    for (int k = 0; k < C; ++k) {
        const float wv = Wb[tid * C + k];
        #pragma unroll
        for (int r = 0; r < ROWS; ++r) acc2[r] += h1[r * C + k] * wv;
    }
    #pragma unroll
    for (int r = 0; r < ROWS; ++r) h2[r * 65 + tid] = tanhf(acc2[r]);
    __syncthreads();

    if (tid < ROWS * 3) {
        const int r = tid / 3, o = tid - r * 3;
        float a = bc[o];
        for (int k = 0; k < C; ++k) a += h2[r * 65 + k] * Wc[o * C + k];
        out[(row0 + r) * 3 + o] = a;
    }
}

extern "C" void kernel_launch(void* const* d_in, const int* in_sizes, int n_in,
                              void* d_out, int out_size, void* d_ws, size_t ws_size,
                              hipStream_t stream)
{
    const float* x       = (const float*)d_in[0];
    const float* pos     = (const float*)d_in[1];
    const float* x_skip2 = (const float*)d_in[3];
    const float* pos2    = (const float*)d_in[4];
    const float* x_skip1 = (const float*)d_in[6];
    const float* pos1    = (const float*)d_in[7];
    const float* x_skip0 = (const float*)d_in[9];
    const float* pos0    = (const float*)d_in[10];
    const float* W3a = (const float*)d_in[12]; const float* b3a = (const float*)d_in[13];
    const float* W3b = (const float*)d_in[14]; const float* b3b = (const float*)d_in[15];
    const float* W2a = (const float*)d_in[16]; const float* b2a = (const float*)d_in[17];
    const float* W2b = (const float*)d_in[18]; const float* b2b = (const float*)d_in[19];
    const float* W1a = (const float*)d_in[20]; const float* b1a = (const float*)d_in[21];
    const float* W1b = (const float*)d_in[22]; const float* b1b = (const float*)d_in[23];
    const float* W1c = (const float*)d_in[24]; const float* b1c = (const float*)d_in[25];

    float* buf1 = (float*)d_ws;                        // 65536*67 floats
    float* buf2 = buf1 + (size_t)65536 * 67;           // 16384*64 floats
    u32*   F1   = (u32*)(buf2 + (size_t)16384 * 64);   // 65536 u32
    u32*   F2   = F1 + 65536;                          // 16384 u32

    // level 3
    knn3_kernel<<<1024, 256, 0, stream>>>(x, pos, pos2, x_skip2, buf1);
    mlp2_kernel<384,128,128,16><<<4096/16, 128, 0, stream>>>(buf1, W3a, b3a, W3b, b3b, buf2, 4096);
    // level 2: select (4 threads/target) + gather (wave-per-target)
    knn_select<8, 256, 10><<<16384*4/256, 256, 0, stream>>>(pos2, pos1, F2);
    knn2_gather<<<4096, 256, 0, stream>>>(buf2, pos2, pos1, x_skip1, F2, buf1);
    mlp2_kernel<192,64,64,16><<<16384/16, 64, 0, stream>>>(buf1, W2a, b2a, W2b, b2b, buf2, 16384);
    // level 1
    knn_select<16, 1024, 12><<<65536*4/256, 256, 0, stream>>>(pos1, pos0, F1);
    knn1_gather<<<16384, 256, 0, stream>>>(buf2, pos1, pos0, x_skip0, F1, buf1);
    mlp_final_kernel<16><<<65536/16, 64, 0, stream>>>(buf1, W1a, b1a, W1b, b1b, W1c, b1c,
                                                      (float*)d_out, 65536);
}

// Round 10
// 289.138 us; speedup vs baseline: 1.3240x; 1.0037x over previous
//
#include <hip/hip_runtime.h>
#include <math.h>

#define DEV __device__ __forceinline__

typedef unsigned long long u64;
typedef unsigned u32;

// monotone map: float bits -> u32 preserving < order (handles negatives)
DEV u32 fmap(float f) {
    u32 b = __float_as_uint(f);
    return b ^ (u32)(((int)b >> 31) | 0x80000000);
}
// exact inverse of fmap
DEV float funmap(u32 m) {
    u32 b = (m & 0x80000000u) ? (m ^ 0x80000000u) : ~m;
    return __uint_as_float(b);
}
DEV u32 umin_(u32 a, u32 b) { return __builtin_elementwise_min(a, b); }
DEV u32 umax_(u32 a, u32 b) { return __builtin_elementwise_max(a, b); }

// ---- BIT-EXACT distance pieces: explicit _rn intrinsics, composed the same
// way in every kernel. pnorm2/qdot/dist2_core are the single source of truth.
DEV float pnorm2(float x, float y, float z) {
    return __fmaf_rn(x, x, __fmaf_rn(y, y, __fmul_rn(z, z)));
}
DEV float qdot(float qx, float qy, float qz, float px, float py, float pz) {
    return __fmaf_rn(qx, px, __fmaf_rn(qy, py, __fmul_rn(qz, pz)));
}
DEV float dist2_core(float qq, float pp, float qp) {
    return __fadd_rn(__fadd_rn(qq, pp), __fmul_rn(-2.f, qp));
}
DEV float dist2(float qx, float qy, float qz, float qq,
                float px, float py, float pz) {
    return dist2_core(qq, pnorm2(px, py, pz), qdot(qx, qy, qz, px, py, pz));
}

// ============ selection kernel: TPT threads per target =====================
template<int K, int NSRC, int LOG_TPG>
__global__ __launch_bounds__(256) void knn_select(
    const float* __restrict__ pos_s, const float* __restrict__ pos_t,
    u32* __restrict__ Fout)
{
    constexpr int TPT = 4;
    constexpr int TPB = 256 / TPT;          // targets per block
    constexpr int SL  = NSRC / TPT;         // slice length per thread
    constexpr int STRIDE = TPT * K + 1;     // +1 pad: conflict-free merge reads
    __shared__ float4 sp[NSRC];
    __shared__ u32 lists[TPB * STRIDE];

    const int tid = threadIdx.x;
    const int w = tid >> 2, sub = tid & 3;
    const int t = blockIdx.x * TPB + w;
    const int g = t >> LOG_TPG, sbase = g * NSRC;

    for (int i = tid; i < NSRC; i += 256) {
        const float* p = pos_s + (size_t)(sbase + i) * 3;
        const float px = p[0], py = p[1], pz = p[2];
        sp[i] = make_float4(px, py, pz, pnorm2(px, py, pz));
    }
    __syncthreads();

    const float qx = pos_t[t*3+0], qy = pos_t[t*3+1], qz = pos_t[t*3+2];
    const float qq = pnorm2(qx, qy, qz);

    u32 r[K];
    #pragma unroll
    for (int j = 0; j < K; ++j) r[j] = 0xFFFFFFFFu;

    #pragma unroll 4
    for (int s = 0; s < SL; ++s) {
        const float4 p = sp[sub * SL + s];
        u32 c = fmap(dist2_core(qq, p.w, qdot(qx, qy, qz, p.x, p.y, p.z)));
        #pragma unroll
        for (int j = 0; j < K; ++j) {
            const u32 lo = umin_(r[j], c);
            c = umax_(r[j], c);
            r[j] = lo;
        }
    }
    u32* Lw = lists + w * STRIDE;
    #pragma unroll
    for (int j = 0; j < K; ++j) Lw[sub * K + j] = r[j];
    __syncthreads();

    if (sub == 0) {
        int i0 = 1, i1 = 1, i2 = 1, i3 = 1;
        u32 h0 = Lw[0*K], h1 = Lw[1*K], h2 = Lw[2*K], h3 = Lw[3*K];
        u32 F = 0;
        #pragma unroll
        for (int step = 0; step < K; ++step) {
            const u32 m = umin_(umin_(h0, h1), umin_(h2, h3));
            F = m;
            if (step < K - 1) {
                if (h0 == m)      { h0 = (i0 < K) ? Lw[0*K + i0] : 0xFFFFFFFFu; ++i0; }
                else if (h1 == m) { h1 = (i1 < K) ? Lw[1*K + i1] : 0xFFFFFFFFu; ++i1; }
                else if (h2 == m) { h2 = (i2 < K) ? Lw[2*K + i2] : 0xFFFFFFFFu; ++i2; }
                else              { h3 = (i3 < K) ? Lw[3*K + i3] : 0xFFFFFFFFu; ++i3; }
            }
        }
        Fout[t] = F;
    }
}

// ============ gather kernels: one wave = one target, LDS-staged positions ==
// Block = 8 waves = 8 targets (same graph). Positions+pp staged in LDS once.

// level 1: k=16, 1024 src/graph, C=64, concat 3 -> out [65536,67]
__global__ __launch_bounds__(512) void knn1_gather(
    const float* __restrict__ xsrc, const float* __restrict__ pos_s,
    const float* __restrict__ pos_t, const float* __restrict__ x_skip,
    const u32* __restrict__ Fbuf, float* __restrict__ out)
{
    __shared__ float4 sp[1024];
    const int lane = threadIdx.x & 63;
    const int t = blockIdx.x * 8 + (threadIdx.x >> 6);
    const int g = (blockIdx.x * 8) >> 12;       // uniform per block
    const int sbase = g << 10;

    for (int i = threadIdx.x; i < 1024; i += 512) {
        const float* p = pos_s + (size_t)(sbase + i) * 3;
        const float px = p[0], py = p[1], pz = p[2];
        sp[i] = make_float4(px, py, pz, pnorm2(px, py, pz));
    }
    __syncthreads();

    const float qx = pos_t[t*3+0], qy = pos_t[t*3+1], qz = pos_t[t*3+2];
    const float qq = pnorm2(qx, qy, qz);
    u32 fm[16];
    #pragma unroll
    for (int m = 0; m < 16; ++m) {
        const float4 p = sp[lane + m*64];
        fm[m] = fmap(dist2_core(qq, p.w, qdot(qx, qy, qz, p.x, p.y, p.z)));
    }
    const u32 F = Fbuf[t];

    float wsum = 0.f, y = 0.f;
    int need = 16;
    #pragma unroll
    for (int m = 0; m < 16; ++m) {
        u64 mask = __ballot(fm[m] < F);
        while (mask && need > 0) {
            const int l = __ffsll((long long)mask) - 1; mask &= mask - 1;
            const float d2 = funmap((u32)__builtin_amdgcn_readlane((int)fm[m], l));
            const float w = __builtin_amdgcn_rcpf(fmaxf(d2, 1e-16f));
            const int row = sbase + l + m*64;
            wsum += w; y += w * xsrc[(size_t)row * 64 + lane];
            --need;
        }
    }
    #pragma unroll
    for (int m = 0; m < 16; ++m) {
        if (need > 0) {
            u64 mask = __ballot(fm[m] == F);
            while (mask && need > 0) {
                const int l = __ffsll((long long)mask) - 1; mask &= mask - 1;
                const float d2 = funmap(F);
                const float w = __builtin_amdgcn_rcpf(fmaxf(d2, 1e-16f));
                const int row = sbase + l + m*64;
                wsum += w; y += w * xsrc[(size_t)row * 64 + lane];
                --need;
            }
        }
    }
    out[t*67 + lane] = y * (1.f / wsum);
    if (lane < 3) out[t*67 + 64 + lane] = x_skip[t*3 + lane];
}

// level 2: k=8, 256 src/graph, C=128, concat 64 -> out [16384,192]
__global__ __launch_bounds__(512) void knn2_gather(
    const float* __restrict__ xsrc, const float* __restrict__ pos_s,
    const float* __restrict__ pos_t, const float* __restrict__ x_skip,
    const u32* __restrict__ Fbuf, float* __restrict__ out)
{
    __shared__ float4 sp[256];
    const int lane = threadIdx.x & 63;
    const int t = blockIdx.x * 8 + (threadIdx.x >> 6);
    const int g = (blockIdx.x * 8) >> 10;       // uniform per block
    const int sbase = g << 8;

    if (threadIdx.x < 256) {
        const int i = threadIdx.x;
        const float* p = pos_s + (size_t)(sbase + i) * 3;
        const float px = p[0], py = p[1], pz = p[2];
        sp[i] = make_float4(px, py, pz, pnorm2(px, py, pz));
    }
    __syncthreads();

    const float qx = pos_t[t*3+0], qy = pos_t[t*3+1], qz = pos_t[t*3+2];
    const float qq = pnorm2(qx, qy, qz);
    u32 fm[4];
    #pragma unroll
    for (int m = 0; m < 4; ++m) {
        const float4 p = sp[lane + m*64];
        fm[m] = fmap(dist2_core(qq, p.w, qdot(qx, qy, qz, p.x, p.y, p.z)));
    }
    const u32 F = Fbuf[t];

    float wsum = 0.f, y0 = 0.f, y1 = 0.f;
    int need = 8;
    #pragma unroll
    for (int m = 0; m < 4; ++m) {
        u64 mask = __ballot(fm[m] < F);
        while (mask && need > 0) {
            const int l = __ffsll((long long)mask) - 1; mask &= mask - 1;
            const float d2 = funmap((u32)__builtin_amdgcn_readlane((int)fm[m], l));
            const float w = __builtin_amdgcn_rcpf(fmaxf(d2, 1e-16f));
            const float* xr = xsrc + (size_t)(sbase + l + m*64) * 128;
            wsum += w; y0 += w * xr[lane]; y1 += w * xr[lane + 64];
            --need;
        }
    }
    #pragma unroll
    for (int m = 0; m < 4; ++m) {
        if (need > 0) {
            u64 mask = __ballot(fm[m] == F);
            while (mask && need > 0) {
                const int l = __ffsll((long long)mask) - 1; mask &= mask - 1;
                const float d2 = funmap(F);
                const float w = __builtin_amdgcn_rcpf(fmaxf(d2, 1e-16f));
                const float* xr = xsrc + (size_t)(sbase + l + m*64) * 128;
                wsum += w; y0 += w * xr[lane]; y1 += w * xr[lane + 64];
                --need;
            }
        }
    }
    const float inv = 1.f / wsum;
    out[t*192 + lane]      = y0 * inv;
    out[t*192 + lane + 64] = y1 * inv;
    out[t*192 + 128 + lane] = x_skip[t*64 + lane];
}

// ---------------- level 3: k=4, 64 src/graph, C=256 -> out [4096,384]
DEV u64 umin64(u64 a, u64 b) { return a < b ? a : b; }
DEV u64 shfl_xor_u64(u64 k, int off) {
    u32 lo = (u32)k, hi = (u32)(k >> 32);
    lo = (u32)__shfl_xor((int)lo, off, 64);
    hi = (u32)__shfl_xor((int)hi, off, 64);
    return ((u64)hi << 32) | lo;
}
DEV u64 wave_min_u64(u64 v) {
    #pragma unroll
    for (int off = 32; off; off >>= 1)
        v = umin64(v, shfl_xor_u64(v, off));
    return v;
}
DEV u64 make_key(float d2, int idx) { return ((u64)fmap(d2) << 10) | (u32)idx; }
DEV float key_weight(u64 k) {
    return __builtin_amdgcn_rcpf(fmaxf(funmap((u32)(k >> 10)), 1e-16f));
}
DEV int key_row(u64 k) {
    return __builtin_amdgcn_readfirstlane((int)((u32)k & 1023u));
}
#define KMAX 0xFFFFFFFFFFFFFFFFull

__global__ __launch_bounds__(256) void knn3_kernel(
    const float* __restrict__ x, const float* __restrict__ pos_s,
    const float* __restrict__ pos_t, const float* __restrict__ x_skip,
    float* __restrict__ out)
{
    const int lane = threadIdx.x & 63;
    const int t = blockIdx.x * 4 + (threadIdx.x >> 6);
    const int g = t >> 8, sbase = g << 6;
    const float qx = pos_t[t*3+0], qy = pos_t[t*3+1], qz = pos_t[t*3+2];
    const float qq = pnorm2(qx, qy, qz);
    const int s = sbase + lane;
    const u64 key = make_key(dist2(qx, qy, qz, qq,
                                   pos_s[s*3+0], pos_s[s*3+1], pos_s[s*3+2]), lane);

    float w[4]; int row[4]; float wsum = 0.f;
    u64 gprev = 0;
    #pragma unroll
    for (int j = 0; j < 4; ++j) {
        gprev = wave_min_u64(key > gprev ? key : KMAX);
        w[j] = key_weight(gprev);
        row[j] = sbase + key_row(gprev);
        wsum += w[j];
    }
    const float inv = 1.f / wsum;
    float y0 = 0.f, y1 = 0.f, y2 = 0.f, y3 = 0.f;
    #pragma unroll
    for (int j = 0; j < 4; ++j) {
        const float* xr = x + (size_t)row[j] * 256;
        y0 += w[j] * xr[lane];
        y1 += w[j] * xr[lane + 64];
        y2 += w[j] * xr[lane + 128];
        y3 += w[j] * xr[lane + 192];
    }
    out[t*384 + lane]       = y0 * inv;
    out[t*384 + lane + 64]  = y1 * inv;
    out[t*384 + lane + 128] = y2 * inv;
    out[t*384 + lane + 192] = y3 * inv;
    out[t*384 + 256 + lane]      = x_skip[t*128 + lane];
    out[t*384 + 256 + 64 + lane] = x_skip[t*128 + 64 + lane];
}

// ---------------- fused 2-layer MLP: out = (tanh(in*Wa^T+ba))*Wb^T+bb
template<int K1, int C1, int C2, int ROWS>
__global__ void mlp2_kernel(
    const float* __restrict__ in, const float* __restrict__ Wa,
    const float* __restrict__ ba, const float* __restrict__ Wb,
    const float* __restrict__ bb, float* __restrict__ out, int N)
{
    __shared__ float xt[ROWS * K1];
    __shared__ float h1[ROWS * C1];
    const int tid = threadIdx.x;
    const int row0 = blockIdx.x * ROWS;

    for (int f = tid; f < ROWS * K1; f += C1)
        xt[f] = in[row0 * K1 + f];
    __syncthreads();

    float acc[ROWS];
    #pragma unroll
    for (int r = 0; r < ROWS; ++r) acc[r] = ba[tid];
    for (int k = 0; k < K1; ++k) {
        const float wv = Wa[tid * K1 + k];
        #pragma unroll
        for (int r = 0; r < ROWS; ++r) acc[r] += xt[r * K1 + k] * wv;
    }
    #pragma unroll
    for (int r = 0; r < ROWS; ++r) h1[r * C1 + tid] = tanhf(acc[r]);
    __syncthreads();

    if (tid < C2) {
        float acc2[ROWS];
        #pragma unroll
        for (int r = 0; r < ROWS; ++r) acc2[r] = bb[tid];
        for (int k = 0; k < C1; ++k) {
            const float wv = Wb[tid * C1 + k];
            #pragma unroll
            for (int r = 0; r < ROWS; ++r) acc2[r] += h1[r * C1 + k] * wv;
        }
        #pragma unroll
        for (int r = 0; r < ROWS; ++r) out[(row0 + r) * C2 + tid] = acc2[r];
    }
}

// ---------------- final 3-layer MLP: 67 -> 64 (tanh) -> 64 (tanh) -> 3
template<int ROWS>
__global__ __launch_bounds__(64) void mlp_final_kernel(
    const float* __restrict__ in,
    const float* __restrict__ Wa, const float* __restrict__ ba,
    const float* __restrict__ Wb, const float* __restrict__ bb,
    const float* __restrict__ Wc, const float* __restrict__ bc,
    float* __restrict__ out, int N)
{
    constexpr int K1 = 67, C = 64;
    __shared__ float xt[ROWS * K1];
    __shared__ float h1[ROWS * C];
    __shared__ float h2[ROWS * 65];
    const int tid = threadIdx.x;
    const int row0 = blockIdx.x * ROWS;

    for (int f = tid; f < ROWS * K1; f += C)
        xt[f] = in[row0 * K1 + f];
    __syncthreads();

    float acc[ROWS];
    #pragma unroll
    for (int r = 0; r < ROWS; ++r) acc[r] = ba[tid];
    for (int k = 0; k < K1; ++k) {
        const float wv = Wa[tid * K1 + k];
        #pragma unroll
        for (int r = 0; r < ROWS; ++r) acc[r] += xt[r * K1 + k] * wv;
    }
    #pragma unroll
    for (int r = 0; r < ROWS; ++r) h1[r * C + tid] = tanhf(acc[r]);
    __syncthreads();

    float acc2[ROWS];
    #pragma unroll
    for (int r = 0; r < ROWS; ++r) acc2[r] = bb[tid];
    for (int k = 0; k < C; ++k) {
        const float wv = Wb[tid * C + k];
        #pragma unroll
        for (int r = 0; r < ROWS; ++r) acc2[r] += h1[r * C + k] * wv;
    }
    #pragma unroll
    for (int r = 0; r < ROWS; ++r) h2[r * 65 + tid] = tanhf(acc2[r]);
    __syncthreads();

    if (tid < ROWS * 3) {
        const int r = tid / 3, o = tid - r * 3;
        float a = bc[o];
        for (int k = 0; k < C; ++k) a += h2[r * 65 + k] * Wc[o * C + k];
        out[(row0 + r) * 3 + o] = a;
    }
}

extern "C" void kernel_launch(void* const* d_in, const int* in_sizes, int n_in,
                              void* d_out, int out_size, void* d_ws, size_t ws_size,
                              hipStream_t stream)
{
    const float* x       = (const float*)d_in[0];
    const float* pos     = (const float*)d_in[1];
    const float* x_skip2 = (const float*)d_in[3];
    const float* pos2    = (const float*)d_in[4];
    const float* x_skip1 = (const float*)d_in[6];
    const float* pos1    = (const float*)d_in[7];
    const float* x_skip0 = (const float*)d_in[9];
    const float* pos0    = (const float*)d_in[10];
    const float* W3a = (const float*)d_in[12]; const float* b3a = (const float*)d_in[13];
    const float* W3b = (const float*)d_in[14]; const float* b3b = (const float*)d_in[15];
    const float* W2a = (const float*)d_in[16]; const float* b2a = (const float*)d_in[17];
    const float* W2b = (const float*)d_in[18]; const float* b2b = (const float*)d_in[19];
    const float* W1a = (const float*)d_in[20]; const float* b1a = (const float*)d_in[21];
    const float* W1b = (const float*)d_in[22]; const float* b1b = (const float*)d_in[23];
    const float* W1c = (const float*)d_in[24]; const float* b1c = (const float*)d_in[25];

    float* buf1 = (float*)d_ws;                        // 65536*67 floats
    float* buf2 = buf1 + (size_t)65536 * 67;           // 16384*64 floats
    u32*   F1   = (u32*)(buf2 + (size_t)16384 * 64);   // 65536 u32
    u32*   F2   = F1 + 65536;                          // 16384 u32

    // level 3
    knn3_kernel<<<1024, 256, 0, stream>>>(x, pos, pos2, x_skip2, buf1);
    mlp2_kernel<384,128,128,16><<<4096/16, 128, 0, stream>>>(buf1, W3a, b3a, W3b, b3b, buf2, 4096);
    // level 2: select (4 threads/target) + gather (8 targets/block, LDS pos)
    knn_select<8, 256, 10><<<16384*4/256, 256, 0, stream>>>(pos2, pos1, F2);
    knn2_gather<<<16384/8, 512, 0, stream>>>(buf2, pos2, pos1, x_skip1, F2, buf1);
    mlp2_kernel<192,64,64,16><<<16384/16, 64, 0, stream>>>(buf1, W2a, b2a, W2b, b2b, buf2, 16384);
    // level 1
    knn_select<16, 1024, 12><<<65536*4/256, 256, 0, stream>>>(pos1, pos0, F1);
    knn1_gather<<<65536/8, 512, 0, stream>>>(buf2, pos1, pos0, x_skip0, F1, buf1);
    mlp_final_kernel<16><<<65536/16, 64, 0, stream>>>(buf1, W1a, b1a, W1b, b1b, W1c, b1c,
                                                      (float*)d_out, 65536);
}

// Round 11
// 263.639 us; speedup vs baseline: 1.4520x; 1.0967x over previous
//
#include <hip/hip_runtime.h>
#include <math.h>

#define DEV __device__ __forceinline__

typedef unsigned long long u64;
typedef unsigned u32;

// monotone map: float bits -> u32 preserving < order (handles negatives)
DEV u32 fmap(float f) {
    u32 b = __float_as_uint(f);
    return b ^ (u32)(((int)b >> 31) | 0x80000000);
}
// exact inverse of fmap
DEV float funmap(u32 m) {
    u32 b = (m & 0x80000000u) ? (m ^ 0x80000000u) : ~m;
    return __uint_as_float(b);
}
DEV u32 umin_(u32 a, u32 b) { return __builtin_elementwise_min(a, b); }
DEV u32 umax_(u32 a, u32 b) { return __builtin_elementwise_max(a, b); }

// ---- BIT-EXACT distance pieces: explicit _rn intrinsics, composed the same
// way in every kernel. pnorm2/qdot/dist2_core are the single source of truth.
DEV float pnorm2(float x, float y, float z) {
    return __fmaf_rn(x, x, __fmaf_rn(y, y, __fmul_rn(z, z)));
}
DEV float qdot(float qx, float qy, float qz, float px, float py, float pz) {
    return __fmaf_rn(qx, px, __fmaf_rn(qy, py, __fmul_rn(qz, pz)));
}
DEV float dist2_core(float qq, float pp, float qp) {
    return __fadd_rn(__fadd_rn(qq, pp), __fmul_rn(-2.f, qp));
}
DEV float dist2(float qx, float qy, float qz, float qq,
                float px, float py, float pz) {
    return dist2_core(qq, pnorm2(px, py, pz), qdot(qx, qy, qz, px, py, pz));
}
DEV float wgt(float d2) { return __builtin_amdgcn_rcpf(fmaxf(d2, 1e-16f)); }

// ============ selection kernel: TPT threads per target =====================
template<int K, int NSRC, int LOG_TPG>
__global__ __launch_bounds__(256) void knn_select(
    const float* __restrict__ pos_s, const float* __restrict__ pos_t,
    u32* __restrict__ Fout)
{
    constexpr int TPT = 4;
    constexpr int TPB = 256 / TPT;          // targets per block
    constexpr int SL  = NSRC / TPT;         // slice length per thread
    constexpr int STRIDE = TPT * K + 1;     // +1 pad: conflict-free merge reads
    __shared__ float4 sp[NSRC];
    __shared__ u32 lists[TPB * STRIDE];

    const int tid = threadIdx.x;
    const int w = tid >> 2, sub = tid & 3;
    const int t = blockIdx.x * TPB + w;
    const int g = t >> LOG_TPG, sbase = g * NSRC;

    for (int i = tid; i < NSRC; i += 256) {
        const float* p = pos_s + (size_t)(sbase + i) * 3;
        const float px = p[0], py = p[1], pz = p[2];
        sp[i] = make_float4(px, py, pz, pnorm2(px, py, pz));
    }
    __syncthreads();

    const float qx = pos_t[t*3+0], qy = pos_t[t*3+1], qz = pos_t[t*3+2];
    const float qq = pnorm2(qx, qy, qz);

    u32 r[K];
    #pragma unroll
    for (int j = 0; j < K; ++j) r[j] = 0xFFFFFFFFu;

    #pragma unroll 4
    for (int s = 0; s < SL; ++s) {
        const float4 p = sp[sub * SL + s];
        u32 c = fmap(dist2_core(qq, p.w, qdot(qx, qy, qz, p.x, p.y, p.z)));
        #pragma unroll
        for (int j = 0; j < K; ++j) {
            const u32 lo = umin_(r[j], c);
            c = umax_(r[j], c);
            r[j] = lo;
        }
    }
    u32* Lw = lists + w * STRIDE;
    #pragma unroll
    for (int j = 0; j < K; ++j) Lw[sub * K + j] = r[j];
    __syncthreads();

    if (sub == 0) {
        int i0 = 1, i1 = 1, i2 = 1, i3 = 1;
        u32 h0 = Lw[0*K], h1 = Lw[1*K], h2 = Lw[2*K], h3 = Lw[3*K];
        u32 F = 0;
        #pragma unroll
        for (int step = 0; step < K; ++step) {
            const u32 m = umin_(umin_(h0, h1), umin_(h2, h3));
            F = m;
            if (step < K - 1) {
                if (h0 == m)      { h0 = (i0 < K) ? Lw[0*K + i0] : 0xFFFFFFFFu; ++i0; }
                else if (h1 == m) { h1 = (i1 < K) ? Lw[1*K + i1] : 0xFFFFFFFFu; ++i1; }
                else if (h2 == m) { h2 = (i2 < K) ? Lw[2*K + i2] : 0xFFFFFFFFu; ++i2; }
                else              { h3 = (i3 < K) ? Lw[3*K + i3] : 0xFFFFFFFFu; ++i3; }
            }
        }
        Fout[t] = F;
    }
}

// ============ gather kernels: one wave = one target ========================
// Parallel extraction: ballot-rank each selected candidate to a slot
// (m-major, lane-minor == index-ascending, matching top_k tie order),
// scatter (row, w) to LDS, then 16 independent pipelined gather loads.

// level 1: k=16, 1024 src/graph, C=64, concat 3 -> out [65536,67]
__global__ __launch_bounds__(512) void knn1_gather(
    const float* __restrict__ xsrc, const float* __restrict__ pos_s,
    const float* __restrict__ pos_t, const float* __restrict__ x_skip,
    const u32* __restrict__ Fbuf, float* __restrict__ out)
{
    constexpr int K = 16, M = 16;
    __shared__ float4 sp[1024];
    __shared__ int  srow[8 * K];
    __shared__ float sw[8 * K];
    const int lane = threadIdx.x & 63;
    const int wv = threadIdx.x >> 6;
    const int t = blockIdx.x * 8 + wv;
    const int g = (blockIdx.x * 8) >> 12;       // uniform per block
    const int sbase = g << 10;

    for (int i = threadIdx.x; i < 1024; i += 512) {
        const float* p = pos_s + (size_t)(sbase + i) * 3;
        const float px = p[0], py = p[1], pz = p[2];
        sp[i] = make_float4(px, py, pz, pnorm2(px, py, pz));
    }
    __syncthreads();

    const float qx = pos_t[t*3+0], qy = pos_t[t*3+1], qz = pos_t[t*3+2];
    const float qq = pnorm2(qx, qy, qz);
    u32 fm[M];
    #pragma unroll
    for (int m = 0; m < M; ++m) {
        const float4 p = sp[lane + m*64];
        fm[m] = fmap(dist2_core(qq, p.w, qdot(qx, qy, qz, p.x, p.y, p.z)));
    }
    const u32 F = Fbuf[t];
    const u64 lt = (1ull << lane) - 1ull;

    // pass 1: count strictly-less
    int nless = 0;
    #pragma unroll
    for (int m = 0; m < M; ++m)
        nless += (int)__popcll(__ballot(fm[m] < F));
    const int need = K - nless;
    const float wtie = wgt(funmap(F));
    const int base = wv * K;

    // pass 2: slot assignment + LDS scatter
    int bl = 0, bt = 0;
    #pragma unroll
    for (int m = 0; m < M; ++m) {
        const u64 mlm = __ballot(fm[m] < F);
        const u64 mtm = __ballot(fm[m] == F);
        if (fm[m] < F) {
            const int slot = bl + (int)__popcll(mlm & lt);
            srow[base + slot] = sbase + lane + m*64;
            sw[base + slot]   = wgt(funmap(fm[m]));
        } else if (fm[m] == F) {
            const int tr = bt + (int)__popcll(mtm & lt);
            if (tr < need) {
                srow[base + nless + tr] = sbase + lane + m*64;
                sw[base + nless + tr]   = wtie;
            }
        }
        bl += (int)__popcll(mlm);
        bt += (int)__popcll(mtm);
    }
    __syncthreads();

    // pipelined gather: 16 independent loads
    float wsum = 0.f, y = 0.f;
    #pragma unroll
    for (int j = 0; j < K; ++j) {
        const int row = srow[base + j];
        const float w = sw[base + j];
        wsum += w;
        y += w * xsrc[(size_t)row * 64 + lane];
    }
    out[t*67 + lane] = y * (1.f / wsum);
    if (lane < 3) out[t*67 + 64 + lane] = x_skip[t*3 + lane];
}

// level 2: k=8, 256 src/graph, C=128, concat 64 -> out [16384,192]
__global__ __launch_bounds__(512) void knn2_gather(
    const float* __restrict__ xsrc, const float* __restrict__ pos_s,
    const float* __restrict__ pos_t, const float* __restrict__ x_skip,
    const u32* __restrict__ Fbuf, float* __restrict__ out)
{
    constexpr int K = 8, M = 4;
    __shared__ float4 sp[256];
    __shared__ int  srow[8 * K];
    __shared__ float sw[8 * K];
    const int lane = threadIdx.x & 63;
    const int wv = threadIdx.x >> 6;
    const int t = blockIdx.x * 8 + wv;
    const int g = (blockIdx.x * 8) >> 10;       // uniform per block
    const int sbase = g << 8;

    if (threadIdx.x < 256) {
        const int i = threadIdx.x;
        const float* p = pos_s + (size_t)(sbase + i) * 3;
        const float px = p[0], py = p[1], pz = p[2];
        sp[i] = make_float4(px, py, pz, pnorm2(px, py, pz));
    }
    __syncthreads();

    const float qx = pos_t[t*3+0], qy = pos_t[t*3+1], qz = pos_t[t*3+2];
    const float qq = pnorm2(qx, qy, qz);
    u32 fm[M];
    #pragma unroll
    for (int m = 0; m < M; ++m) {
        const float4 p = sp[lane + m*64];
        fm[m] = fmap(dist2_core(qq, p.w, qdot(qx, qy, qz, p.x, p.y, p.z)));
    }
    const u32 F = Fbuf[t];
    const u64 lt = (1ull << lane) - 1ull;

    int nless = 0;
    #pragma unroll
    for (int m = 0; m < M; ++m)
        nless += (int)__popcll(__ballot(fm[m] < F));
    const int need = K - nless;
    const float wtie = wgt(funmap(F));
    const int base = wv * K;

    int bl = 0, bt = 0;
    #pragma unroll
    for (int m = 0; m < M; ++m) {
        const u64 mlm = __ballot(fm[m] < F);
        const u64 mtm = __ballot(fm[m] == F);
        if (fm[m] < F) {
            const int slot = bl + (int)__popcll(mlm & lt);
            srow[base + slot] = sbase + lane + m*64;
            sw[base + slot]   = wgt(funmap(fm[m]));
        } else if (fm[m] == F) {
            const int tr = bt + (int)__popcll(mtm & lt);
            if (tr < need) {
                srow[base + nless + tr] = sbase + lane + m*64;
                sw[base + nless + tr]   = wtie;
            }
        }
        bl += (int)__popcll(mlm);
        bt += (int)__popcll(mtm);
    }
    __syncthreads();

    float wsum = 0.f, y0 = 0.f, y1 = 0.f;
    #pragma unroll
    for (int j = 0; j < K; ++j) {
        const int row = srow[base + j];
        const float w = sw[base + j];
        const float* xr = xsrc + (size_t)row * 128;
        wsum += w;
        y0 += w * xr[lane];
        y1 += w * xr[lane + 64];
    }
    const float inv = 1.f / wsum;
    out[t*192 + lane]      = y0 * inv;
    out[t*192 + lane + 64] = y1 * inv;
    out[t*192 + 128 + lane] = x_skip[t*64 + lane];
}

// ---------------- level 3: k=4, 64 src/graph, C=256 -> out [4096,384]
DEV u64 umin64(u64 a, u64 b) { return a < b ? a : b; }
DEV u64 shfl_xor_u64(u64 k, int off) {
    u32 lo = (u32)k, hi = (u32)(k >> 32);
    lo = (u32)__shfl_xor((int)lo, off, 64);
    hi = (u32)__shfl_xor((int)hi, off, 64);
    return ((u64)hi << 32) | lo;
}
DEV u64 wave_min_u64(u64 v) {
    #pragma unroll
    for (int off = 32; off; off >>= 1)
        v = umin64(v, shfl_xor_u64(v, off));
    return v;
}
DEV u64 make_key(float d2, int idx) { return ((u64)fmap(d2) << 10) | (u32)idx; }
DEV float key_weight(u64 k) {
    return __builtin_amdgcn_rcpf(fmaxf(funmap((u32)(k >> 10)), 1e-16f));
}
DEV int key_row(u64 k) {
    return __builtin_amdgcn_readfirstlane((int)((u32)k & 1023u));
}
#define KMAX 0xFFFFFFFFFFFFFFFFull

__global__ __launch_bounds__(256) void knn3_kernel(
    const float* __restrict__ x, const float* __restrict__ pos_s,
    const float* __restrict__ pos_t, const float* __restrict__ x_skip,
    float* __restrict__ out)
{
    const int lane = threadIdx.x & 63;
    const int t = blockIdx.x * 4 + (threadIdx.x >> 6);
    const int g = t >> 8, sbase = g << 6;
    const float qx = pos_t[t*3+0], qy = pos_t[t*3+1], qz = pos_t[t*3+2];
    const float qq = pnorm2(qx, qy, qz);
    const int s = sbase + lane;
    const u64 key = make_key(dist2(qx, qy, qz, qq,
                                   pos_s[s*3+0], pos_s[s*3+1], pos_s[s*3+2]), lane);

    float w[4]; int row[4]; float wsum = 0.f;
    u64 gprev = 0;
    #pragma unroll
    for (int j = 0; j < 4; ++j) {
        gprev = wave_min_u64(key > gprev ? key : KMAX);
        w[j] = key_weight(gprev);
        row[j] = sbase + key_row(gprev);
        wsum += w[j];
    }
    const float inv = 1.f / wsum;
    float y0 = 0.f, y1 = 0.f, y2 = 0.f, y3 = 0.f;
    #pragma unroll
    for (int j = 0; j < 4; ++j) {
        const float* xr = x + (size_t)row[j] * 256;
        y0 += w[j] * xr[lane];
        y1 += w[j] * xr[lane + 64];
        y2 += w[j] * xr[lane + 128];
        y3 += w[j] * xr[lane + 192];
    }
    out[t*384 + lane]       = y0 * inv;
    out[t*384 + lane + 64]  = y1 * inv;
    out[t*384 + lane + 128] = y2 * inv;
    out[t*384 + lane + 192] = y3 * inv;
    out[t*384 + 256 + lane]      = x_skip[t*128 + lane];
    out[t*384 + 256 + 64 + lane] = x_skip[t*128 + 64 + lane];
}

// ---------------- fused 2-layer MLP: out = (tanh(in*Wa^T+ba))*Wb^T+bb
template<int K1, int C1, int C2, int ROWS>
__global__ void mlp2_kernel(
    const float* __restrict__ in, const float* __restrict__ Wa,
    const float* __restrict__ ba, const float* __restrict__ Wb,
    const float* __restrict__ bb, float* __restrict__ out, int N)
{
    __shared__ float xt[ROWS * K1];
    __shared__ float h1[ROWS * C1];
    const int tid = threadIdx.x;
    const int row0 = blockIdx.x * ROWS;

    for (int f = tid; f < ROWS * K1; f += C1)
        xt[f] = in[row0 * K1 + f];
    __syncthreads();

    float acc[ROWS];
    #pragma unroll
    for (int r = 0; r < ROWS; ++r) acc[r] = ba[tid];
    for (int k = 0; k < K1; ++k) {
        const float wv = Wa[tid * K1 + k];
        #pragma unroll
        for (int r = 0; r < ROWS; ++r) acc[r] += xt[r * K1 + k] * wv;
    }
    #pragma unroll
    for (int r = 0; r < ROWS; ++r) h1[r * C1 + tid] = tanhf(acc[r]);
    __syncthreads();

    if (tid < C2) {
        float acc2[ROWS];
        #pragma unroll
        for (int r = 0; r < ROWS; ++r) acc2[r] = bb[tid];
        for (int k = 0; k < C1; ++k) {
            const float wv = Wb[tid * C1 + k];
            #pragma unroll
            for (int r = 0; r < ROWS; ++r) acc2[r] += h1[r * C1 + k] * wv;
        }
        #pragma unroll
        for (int r = 0; r < ROWS; ++r) out[(row0 + r) * C2 + tid] = acc2[r];
    }
}

// ---------------- final 3-layer MLP: 67 -> 64 (tanh) -> 64 (tanh) -> 3
template<int ROWS>
__global__ __launch_bounds__(64) void mlp_final_kernel(
    const float* __restrict__ in,
    const float* __restrict__ Wa, const float* __restrict__ ba,
    const float* __restrict__ Wb, const float* __restrict__ bb,
    const float* __restrict__ Wc, const float* __restrict__ bc,
    float* __restrict__ out, int N)
{
    constexpr int K1 = 67, C = 64;
    __shared__ float xt[ROWS * K1];
    __shared__ float h1[ROWS * C];
    __shared__ float h2[ROWS * 65];
    const int tid = threadIdx.x;
    const int row0 = blockIdx.x * ROWS;

    for (int f = tid; f < ROWS * K1; f += C)
        xt[f] = in[row0 * K1 + f];
    __syncthreads();

    float acc[ROWS];
    #pragma unroll
    for (int r = 0; r < ROWS; ++r) acc[r] = ba[tid];
    for (int k = 0; k < K1; ++k) {
        const float wv = Wa[tid * K1 + k];
        #pragma unroll
        for (int r = 0; r < ROWS; ++r) acc[r] += xt[r * K1 + k] * wv;
    }
    #pragma unroll
    for (int r = 0; r < ROWS; ++r) h1[r * C + tid] = tanhf(acc[r]);
    __syncthreads();

    float acc2[ROWS];
    #pragma unroll
    for (int r = 0; r < ROWS; ++r) acc2[r] = bb[tid];
    for (int k = 0; k < C; ++k) {
        const float wv = Wb[tid * C + k];
        #pragma unroll
        for (int r = 0; r < ROWS; ++r) acc2[r] += h1[r * C + k] * wv;
    }
    #pragma unroll
    for (int r = 0; r < ROWS; ++r) h2[r * 65 + tid] = tanhf(acc2[r]);
    __syncthreads();

    if (tid < ROWS * 3) {
        const int r = tid / 3, o = tid - r * 3;
        float a = bc[o];
        for (int k = 0; k < C; ++k) a += h2[r * 65 + k] * Wc[o * C + k];
        out[(row0 + r) * 3 + o] = a;
    }
}

extern "C" void kernel_launch(void* const* d_in, const int* in_sizes, int n_in,
                              void* d_out, int out_size, void* d_ws, size_t ws_size,
                              hipStream_t stream)
{
    const float* x       = (const float*)d_in[0];
    const float* pos     = (const float*)d_in[1];
    const float* x_skip2 = (const float*)d_in[3];
    const float* pos2    = (const float*)d_in[4];
    const float* x_skip1 = (const float*)d_in[6];
    const float* pos1    = (const float*)d_in[7];
    const float* x_skip0 = (const float*)d_in[9];
    const float* pos0    = (const float*)d_in[10];
    const float* W3a = (const float*)d_in[12]; const float* b3a = (const float*)d_in[13];
    const float* W3b = (const float*)d_in[14]; const float* b3b = (const float*)d_in[15];
    const float* W2a = (const float*)d_in[16]; const float* b2a = (const float*)d_in[17];
    const float* W2b = (const float*)d_in[18]; const float* b2b = (const float*)d_in[19];
    const float* W1a = (const float*)d_in[20]; const float* b1a = (const float*)d_in[21];
    const float* W1b = (const float*)d_in[22]; const float* b1b = (const float*)d_in[23];
    const float* W1c = (const float*)d_in[24]; const float* b1c = (const float*)d_in[25];

    float* buf1 = (float*)d_ws;                        // 65536*67 floats
    float* buf2 = buf1 + (size_t)65536 * 67;           // 16384*64 floats
    u32*   F1   = (u32*)(buf2 + (size_t)16384 * 64);   // 65536 u32
    u32*   F2   = F1 + 65536;                          // 16384 u32

    // level 3
    knn3_kernel<<<1024, 256, 0, stream>>>(x, pos, pos2, x_skip2, buf1);
    mlp2_kernel<384,128,128,16><<<4096/16, 128, 0, stream>>>(buf1, W3a, b3a, W3b, b3b, buf2, 4096);
    // level 2: select (4 threads/target) + gather (8 targets/block, LDS pos)
    knn_select<8, 256, 10><<<16384*4/256, 256, 0, stream>>>(pos2, pos1, F2);
    knn2_gather<<<16384/8, 512, 0, stream>>>(buf2, pos2, pos1, x_skip1, F2, buf1);
    mlp2_kernel<192,64,64,16><<<16384/16, 64, 0, stream>>>(buf1, W2a, b2a, W2b, b2b, buf2, 16384);
    // level 1
    knn_select<16, 1024, 12><<<65536*4/256, 256, 0, stream>>>(pos1, pos0, F1);
    knn1_gather<<<65536/8, 512, 0, stream>>>(buf2, pos1, pos0, x_skip0, F1, buf1);
    mlp_final_kernel<16><<<65536/16, 64, 0, stream>>>(buf1, W1a, b1a, W1b, b1b, W1c, b1c,
                                                      (float*)d_out, 65536);
}

// Round 12
// 261.360 us; speedup vs baseline: 1.4647x; 1.0087x over previous
//
#include <hip/hip_runtime.h>
#include <math.h>

#define DEV __device__ __forceinline__

typedef unsigned long long u64;
typedef unsigned u32;

// monotone map: float bits -> u32 preserving < order (handles negatives)
DEV u32 fmap(float f) {
    u32 b = __float_as_uint(f);
    return b ^ (u32)(((int)b >> 31) | 0x80000000);
}
// exact inverse of fmap
DEV float funmap(u32 m) {
    u32 b = (m & 0x80000000u) ? (m ^ 0x80000000u) : ~m;
    return __uint_as_float(b);
}
DEV u32 umin_(u32 a, u32 b) { return __builtin_elementwise_min(a, b); }
DEV u32 umax_(u32 a, u32 b) { return __builtin_elementwise_max(a, b); }

// ---- BIT-EXACT distance pieces: explicit _rn intrinsics, composed the same
// way in every kernel.
DEV float pnorm2(float x, float y, float z) {
    return __fmaf_rn(x, x, __fmaf_rn(y, y, __fmul_rn(z, z)));
}
DEV float qdot(float qx, float qy, float qz, float px, float py, float pz) {
    return __fmaf_rn(qx, px, __fmaf_rn(qy, py, __fmul_rn(qz, pz)));
}
DEV float dist2_core(float qq, float pp, float qp) {
    return __fadd_rn(__fadd_rn(qq, pp), __fmul_rn(-2.f, qp));
}
DEV float dist2(float qx, float qy, float qz, float qq,
                float px, float py, float pz) {
    return dist2_core(qq, pnorm2(px, py, pz), qdot(qx, qy, qz, px, py, pz));
}
DEV float wgt(float d2) { return __builtin_amdgcn_rcpf(fmaxf(d2, 1e-16f)); }

// ---- bitonic helpers: compile-time indices only (registers stay registers)
template<int N>
DEV void bitonic_sort(u32 v[N]) {           // full ascending sort
    #pragma unroll
    for (int k = 2; k <= N; k <<= 1) {
        #pragma unroll
        for (int j = k >> 1; j > 0; j >>= 1) {
            #pragma unroll
            for (int i = 0; i < N; ++i) {
                const int l = i ^ j;
                if (l > i) {
                    const u32 lo = umin_(v[i], v[l]);
                    const u32 hi = umax_(v[i], v[l]);
                    const bool up = ((i & k) == 0);
                    v[i] = up ? lo : hi;
                    v[l] = up ? hi : lo;
                }
            }
        }
    }
}
template<int N>
DEV void bitonic_cleanup(u32 v[N]) {        // sort a bitonic sequence ascending
    #pragma unroll
    for (int j = N >> 1; j > 0; j >>= 1) {
        #pragma unroll
        for (int i = 0; i < N; ++i) {
            const int l = i ^ j;
            if (l > i) {
                const u32 lo = umin_(v[i], v[l]);
                v[l] = umax_(v[i], v[l]);
                v[i] = lo;
            }
        }
    }
}
// butterfly merge: every lane ends with the wave's sorted N smallest keys
template<int N>
DEV void wave_topk(u32 r[N]) {
    #pragma unroll
    for (int d = 1; d < 64; d <<= 1) {
        u32 b[N];
        #pragma unroll
        for (int i = 0; i < N; ++i) b[i] = (u32)__shfl_xor((int)r[i], d, 64);
        u32 t[N];
        #pragma unroll
        for (int i = 0; i < N; ++i) t[i] = umin_(r[i], b[N-1-i]);
        bitonic_cleanup<N>(t);
        #pragma unroll
        for (int i = 0; i < N; ++i) r[i] = t[i];
    }
}

// ============ fused kNN kernels: one wave = one target =====================
// Build fm[] from LDS-staged positions, find F (k-th smallest key) via
// in-wave bitonic top-K, then ballot-rank compaction + pipelined gather.

// level 1: k=16, 1024 src/graph, C=64, concat 3 -> out [65536,67]
__global__ __launch_bounds__(512) void knn1_gather(
    const float* __restrict__ xsrc, const float* __restrict__ pos_s,
    const float* __restrict__ pos_t, const float* __restrict__ x_skip,
    float* __restrict__ out)
{
    constexpr int K = 16, M = 16;
    __shared__ float4 sp[1024];
    __shared__ int  srow[8 * K];
    __shared__ float sw[8 * K];
    const int lane = threadIdx.x & 63;
    const int wv = threadIdx.x >> 6;
    const int t = blockIdx.x * 8 + wv;
    const int g = (blockIdx.x * 8) >> 12;       // uniform per block
    const int sbase = g << 10;

    for (int i = threadIdx.x; i < 1024; i += 512) {
        const float* p = pos_s + (size_t)(sbase + i) * 3;
        const float px = p[0], py = p[1], pz = p[2];
        sp[i] = make_float4(px, py, pz, pnorm2(px, py, pz));
    }
    __syncthreads();

    const float qx = pos_t[t*3+0], qy = pos_t[t*3+1], qz = pos_t[t*3+2];
    const float qq = pnorm2(qx, qy, qz);
    u32 fm[M];
    #pragma unroll
    for (int m = 0; m < M; ++m) {
        const float4 p = sp[lane + m*64];
        fm[m] = fmap(dist2_core(qq, p.w, qdot(qx, qy, qz, p.x, p.y, p.z)));
    }

    // ---- in-wave exact top-K: F = K-th smallest key in the wave
    u32 r[K];
    #pragma unroll
    for (int m = 0; m < M; ++m) r[m] = fm[m];
    bitonic_sort<K>(r);
    wave_topk<K>(r);
    const u32 F = r[K-1];

    const u64 lt = (1ull << lane) - 1ull;

    // pass 1: count strictly-less
    int nless = 0;
    #pragma unroll
    for (int m = 0; m < M; ++m)
        nless += (int)__popcll(__ballot(fm[m] < F));
    const int need = K - nless;
    const float wtie = wgt(funmap(F));
    const int base = wv * K;

    // pass 2: slot assignment + LDS scatter (index-ascending == top_k order)
    int bl = 0, bt = 0;
    #pragma unroll
    for (int m = 0; m < M; ++m) {
        const u64 mlm = __ballot(fm[m] < F);
        const u64 mtm = __ballot(fm[m] == F);
        if (fm[m] < F) {
            const int slot = bl + (int)__popcll(mlm & lt);
            srow[base + slot] = sbase + lane + m*64;
            sw[base + slot]   = wgt(funmap(fm[m]));
        } else if (fm[m] == F) {
            const int tr = bt + (int)__popcll(mtm & lt);
            if (tr < need) {
                srow[base + nless + tr] = sbase + lane + m*64;
                sw[base + nless + tr]   = wtie;
            }
        }
        bl += (int)__popcll(mlm);
        bt += (int)__popcll(mtm);
    }
    __syncthreads();

    // pipelined gather: 16 independent loads
    float wsum = 0.f, y = 0.f;
    #pragma unroll
    for (int j = 0; j < K; ++j) {
        const int row = srow[base + j];
        const float w = sw[base + j];
        wsum += w;
        y += w * xsrc[(size_t)row * 64 + lane];
    }
    out[t*67 + lane] = y * (1.f / wsum);
    if (lane < 3) out[t*67 + 64 + lane] = x_skip[t*3 + lane];
}

// level 2: k=8, 256 src/graph, C=128, concat 64 -> out [16384,192]
__global__ __launch_bounds__(512) void knn2_gather(
    const float* __restrict__ xsrc, const float* __restrict__ pos_s,
    const float* __restrict__ pos_t, const float* __restrict__ x_skip,
    float* __restrict__ out)
{
    constexpr int K = 8, M = 4;
    __shared__ float4 sp[256];
    __shared__ int  srow[8 * K];
    __shared__ float sw[8 * K];
    const int lane = threadIdx.x & 63;
    const int wv = threadIdx.x >> 6;
    const int t = blockIdx.x * 8 + wv;
    const int g = (blockIdx.x * 8) >> 10;       // uniform per block
    const int sbase = g << 8;

    if (threadIdx.x < 256) {
        const int i = threadIdx.x;
        const float* p = pos_s + (size_t)(sbase + i) * 3;
        const float px = p[0], py = p[1], pz = p[2];
        sp[i] = make_float4(px, py, pz, pnorm2(px, py, pz));
    }
    __syncthreads();

    const float qx = pos_t[t*3+0], qy = pos_t[t*3+1], qz = pos_t[t*3+2];
    const float qq = pnorm2(qx, qy, qz);
    u32 fm[M];
    #pragma unroll
    for (int m = 0; m < M; ++m) {
        const float4 p = sp[lane + m*64];
        fm[m] = fmap(dist2_core(qq, p.w, qdot(qx, qy, qz, p.x, p.y, p.z)));
    }

    // ---- in-wave exact top-K (pad with sentinels to K=8)
    u32 r[K];
    #pragma unroll
    for (int m = 0; m < M; ++m) r[m] = fm[m];
    #pragma unroll
    for (int m = M; m < K; ++m) r[m] = 0xFFFFFFFFu;
    bitonic_sort<K>(r);
    wave_topk<K>(r);
    const u32 F = r[K-1];

    const u64 lt = (1ull << lane) - 1ull;

    int nless = 0;
    #pragma unroll
    for (int m = 0; m < M; ++m)
        nless += (int)__popcll(__ballot(fm[m] < F));
    const int need = K - nless;
    const float wtie = wgt(funmap(F));
    const int base = wv * K;

    int bl = 0, bt = 0;
    #pragma unroll
    for (int m = 0; m < M; ++m) {
        const u64 mlm = __ballot(fm[m] < F);
        const u64 mtm = __ballot(fm[m] == F);
        if (fm[m] < F) {
            const int slot = bl + (int)__popcll(mlm & lt);
            srow[base + slot] = sbase + lane + m*64;
            sw[base + slot]   = wgt(funmap(fm[m]));
        } else if (fm[m] == F) {
            const int tr = bt + (int)__popcll(mtm & lt);
            if (tr < need) {
                srow[base + nless + tr] = sbase + lane + m*64;
                sw[base + nless + tr]   = wtie;
            }
        }
        bl += (int)__popcll(mlm);
        bt += (int)__popcll(mtm);
    }
    __syncthreads();

    float wsum = 0.f, y0 = 0.f, y1 = 0.f;
    #pragma unroll
    for (int j = 0; j < K; ++j) {
        const int row = srow[base + j];
        const float w = sw[base + j];
        const float* xr = xsrc + (size_t)row * 128;
        wsum += w;
        y0 += w * xr[lane];
        y1 += w * xr[lane + 64];
    }
    const float inv = 1.f / wsum;
    out[t*192 + lane]      = y0 * inv;
    out[t*192 + lane + 64] = y1 * inv;
    out[t*192 + 128 + lane] = x_skip[t*64 + lane];
}

// ---------------- level 3: k=4, 64 src/graph, C=256 -> out [4096,384]
DEV u64 umin64(u64 a, u64 b) { return a < b ? a : b; }
DEV u64 shfl_xor_u64(u64 k, int off) {
    u32 lo = (u32)k, hi = (u32)(k >> 32);
    lo = (u32)__shfl_xor((int)lo, off, 64);
    hi = (u32)__shfl_xor((int)hi, off, 64);
    return ((u64)hi << 32) | lo;
}
DEV u64 wave_min_u64(u64 v) {
    #pragma unroll
    for (int off = 32; off; off >>= 1)
        v = umin64(v, shfl_xor_u64(v, off));
    return v;
}
DEV u64 make_key(float d2, int idx) { return ((u64)fmap(d2) << 10) | (u32)idx; }
DEV float key_weight(u64 k) {
    return __builtin_amdgcn_rcpf(fmaxf(funmap((u32)(k >> 10)), 1e-16f));
}
DEV int key_row(u64 k) {
    return __builtin_amdgcn_readfirstlane((int)((u32)k & 1023u));
}
#define KMAX 0xFFFFFFFFFFFFFFFFull

__global__ __launch_bounds__(256) void knn3_kernel(
    const float* __restrict__ x, const float* __restrict__ pos_s,
    const float* __restrict__ pos_t, const float* __restrict__ x_skip,
    float* __restrict__ out)
{
    const int lane = threadIdx.x & 63;
    const int t = blockIdx.x * 4 + (threadIdx.x >> 6);
    const int g = t >> 8, sbase = g << 6;
    const float qx = pos_t[t*3+0], qy = pos_t[t*3+1], qz = pos_t[t*3+2];
    const float qq = pnorm2(qx, qy, qz);
    const int s = sbase + lane;
    const u64 key = make_key(dist2(qx, qy, qz, qq,
                                   pos_s[s*3+0], pos_s[s*3+1], pos_s[s*3+2]), lane);

    float w[4]; int row[4]; float wsum = 0.f;
    u64 gprev = 0;
    #pragma unroll
    for (int j = 0; j < 4; ++j) {
        gprev = wave_min_u64(key > gprev ? key : KMAX);
        w[j] = key_weight(gprev);
        row[j] = sbase + key_row(gprev);
        wsum += w[j];
    }
    const float inv = 1.f / wsum;
    float y0 = 0.f, y1 = 0.f, y2 = 0.f, y3 = 0.f;
    #pragma unroll
    for (int j = 0; j < 4; ++j) {
        const float* xr = x + (size_t)row[j] * 256;
        y0 += w[j] * xr[lane];
        y1 += w[j] * xr[lane + 64];
        y2 += w[j] * xr[lane + 128];
        y3 += w[j] * xr[lane + 192];
    }
    out[t*384 + lane]       = y0 * inv;
    out[t*384 + lane + 64]  = y1 * inv;
    out[t*384 + lane + 128] = y2 * inv;
    out[t*384 + lane + 192] = y3 * inv;
    out[t*384 + 256 + lane]      = x_skip[t*128 + lane];
    out[t*384 + 256 + 64 + lane] = x_skip[t*128 + 64 + lane];
}

// ---------------- fused 2-layer MLP: out = (tanh(in*Wa^T+ba))*Wb^T+bb
template<int K1, int C1, int C2, int ROWS>
__global__ void mlp2_kernel(
    const float* __restrict__ in, const float* __restrict__ Wa,
    const float* __restrict__ ba, const float* __restrict__ Wb,
    const float* __restrict__ bb, float* __restrict__ out, int N)
{
    __shared__ float xt[ROWS * K1];
    __shared__ float h1[ROWS * C1];
    const int tid = threadIdx.x;
    const int row0 = blockIdx.x * ROWS;

    for (int f = tid; f < ROWS * K1; f += C1)
        xt[f] = in[row0 * K1 + f];
    __syncthreads();

    float acc[ROWS];
    #pragma unroll
    for (int r = 0; r < ROWS; ++r) acc[r] = ba[tid];
    for (int k = 0; k < K1; ++k) {
        const float wv = Wa[tid * K1 + k];
        #pragma unroll
        for (int r = 0; r < ROWS; ++r) acc[r] += xt[r * K1 + k] * wv;
    }
    #pragma unroll
    for (int r = 0; r < ROWS; ++r) h1[r * C1 + tid] = tanhf(acc[r]);
    __syncthreads();

    if (tid < C2) {
        float acc2[ROWS];
        #pragma unroll
        for (int r = 0; r < ROWS; ++r) acc2[r] = bb[tid];
        for (int k = 0; k < C1; ++k) {
            const float wv = Wb[tid * C1 + k];
            #pragma unroll
            for (int r = 0; r < ROWS; ++r) acc2[r] += h1[r * C1 + k] * wv;
        }
        #pragma unroll
        for (int r = 0; r < ROWS; ++r) out[(row0 + r) * C2 + tid] = acc2[r];
    }
}

// ---------------- final 3-layer MLP: 67 -> 64 (tanh) -> 64 (tanh) -> 3
template<int ROWS>
__global__ __launch_bounds__(64) void mlp_final_kernel(
    const float* __restrict__ in,
    const float* __restrict__ Wa, const float* __restrict__ ba,
    const float* __restrict__ Wb, const float* __restrict__ bb,
    const float* __restrict__ Wc, const float* __restrict__ bc,
    float* __restrict__ out, int N)
{
    constexpr int K1 = 67, C = 64;
    __shared__ float xt[ROWS * K1];
    __shared__ float h1[ROWS * C];
    __shared__ float h2[ROWS * 65];
    const int tid = threadIdx.x;
    const int row0 = blockIdx.x * ROWS;

    for (int f = tid; f < ROWS * K1; f += C)
        xt[f] = in[row0 * K1 + f];
    __syncthreads();

    float acc[ROWS];
    #pragma unroll
    for (int r = 0; r < ROWS; ++r) acc[r] = ba[tid];
    for (int k = 0; k < K1; ++k) {
        const float wv = Wa[tid * K1 + k];
        #pragma unroll
        for (int r = 0; r < ROWS; ++r) acc[r] += xt[r * K1 + k] * wv;
    }
    #pragma unroll
    for (int r = 0; r < ROWS; ++r) h1[r * C + tid] = tanhf(acc[r]);
    __syncthreads();

    float acc2[ROWS];
    #pragma unroll
    for (int r = 0; r < ROWS; ++r) acc2[r] = bb[tid];
    for (int k = 0; k < C; ++k) {
        const float wv = Wb[tid * C + k];
        #pragma unroll
        for (int r = 0; r < ROWS; ++r) acc2[r] += h1[r * C + k] * wv;
    }
    #pragma unroll
    for (int r = 0; r < ROWS; ++r) h2[r * 65 + tid] = tanhf(acc2[r]);
    __syncthreads();

    if (tid < ROWS * 3) {
        const int r = tid / 3, o = tid - r * 3;
        float a = bc[o];
        for (int k = 0; k < C; ++k) a += h2[r * 65 + k] * Wc[o * C + k];
        out[(row0 + r) * 3 + o] = a;
    }
}

extern "C" void kernel_launch(void* const* d_in, const int* in_sizes, int n_in,
                              void* d_out, int out_size, void* d_ws, size_t ws_size,
                              hipStream_t stream)
{
    const float* x       = (const float*)d_in[0];
    const float* pos     = (const float*)d_in[1];
    const float* x_skip2 = (const float*)d_in[3];
    const float* pos2    = (const float*)d_in[4];
    const float* x_skip1 = (const float*)d_in[6];
    const float* pos1    = (const float*)d_in[7];
    const float* x_skip0 = (const float*)d_in[9];
    const float* pos0    = (const float*)d_in[10];
    const float* W3a = (const float*)d_in[12]; const float* b3a = (const float*)d_in[13];
    const float* W3b = (const float*)d_in[14]; const float* b3b = (const float*)d_in[15];
    const float* W2a = (const float*)d_in[16]; const float* b2a = (const float*)d_in[17];
    const float* W2b = (const float*)d_in[18]; const float* b2b = (const float*)d_in[19];
    const float* W1a = (const float*)d_in[20]; const float* b1a = (const float*)d_in[21];
    const float* W1b = (const float*)d_in[22]; const float* b1b = (const float*)d_in[23];
    const float* W1c = (const float*)d_in[24]; const float* b1c = (const float*)d_in[25];

    float* buf1 = (float*)d_ws;                        // 65536*67 floats
    float* buf2 = buf1 + (size_t)65536 * 67;           // 16384*64 floats

    // level 3
    knn3_kernel<<<1024, 256, 0, stream>>>(x, pos, pos2, x_skip2, buf1);
    mlp2_kernel<384,128,128,16><<<4096/16, 128, 0, stream>>>(buf1, W3a, b3a, W3b, b3b, buf2, 4096);
    // level 2 (fused select+gather)
    knn2_gather<<<16384/8, 512, 0, stream>>>(buf2, pos2, pos1, x_skip1, buf1);
    mlp2_kernel<192,64,64,16><<<16384/16, 64, 0, stream>>>(buf1, W2a, b2a, W2b, b2b, buf2, 16384);
    // level 1 (fused select+gather)
    knn1_gather<<<65536/8, 512, 0, stream>>>(buf2, pos1, pos0, x_skip0, buf1);
    mlp_final_kernel<16><<<65536/16, 64, 0, stream>>>(buf1, W1a, b1a, W1b, b1b, W1c, b1c,
                                                      (float*)d_out, 65536);
}